// Round 4
// baseline (230.292 us; speedup 1.0000x reference)
//
#include <hip/hip_runtime.h>
#include <hip/hip_bf16.h>

typedef __attribute__((ext_vector_type(2))) _Float16 f16x2;
typedef __attribute__((ext_vector_type(8))) _Float16 f16x8;
typedef __attribute__((ext_vector_type(4))) float    f32x4;

#define GRID_ELEMS (8*64*64*64)   // 2,097,152 voxels at level 0

// --------------------------------------------- scatter + weight-repack combo
// blocks [0,324): repack W1/W2/W3 -> W1pk / W2hT / W3hT
// blocks [324, ..): scatter points (atomicAdd grid, atomicOr mask bits)
__global__ __launch_bounds__(256) void scatter_setup_k(
    const int* __restrict__ coords, const float* __restrict__ feats,
    const float* __restrict__ W1, const float* __restrict__ W2, const float* __restrict__ W3,
    float* __restrict__ grid, unsigned* __restrict__ bits,
    _Float16* __restrict__ W2hT, _Float16* __restrict__ W3hT, unsigned* __restrict__ W1pk,
    int N)
{
  const int bi = blockIdx.x;
  if (bi < 324) {
    int i = bi * 256 + threadIdx.x;
    if (i < 16384) {                       // W2hT[o][k=p*32+c]
      int o = i >> 8, k = i & 255, p = k >> 5, c = k & 31;
      W2hT[i] = (_Float16)W2[p * 2048 + c * 64 + o];
    }
    int j = i - 16384;
    if (j >= 0 && j < 65536) {             // W3hT[o][k=p*64+c]
      int o = j >> 9, k = j & 511, p = k >> 6, c = k & 63;
      W3hT[j] = (_Float16)W3[p * 8192 + c * 128 + o];
    }
    int t = i - (16384 + 65536);
    if (t >= 0 && t < 864) {               // W1pk = dup-f16
      _Float16 w = (_Float16)W1[t];
      f16x2 v; v.x = w; v.y = w;
      W1pk[t] = __builtin_bit_cast(unsigned, v);
    }
    return;
  }
  int i = (bi - 324) * 256 + threadIdx.x;
  if (i >= N) return;
  const int4 c = reinterpret_cast<const int4*>(coords)[i];
  atomicAdd(&grid[((c.x * 64 + c.y) * 64 + c.z) * 64 + c.w], feats[i]);
  atomicOr(&bits[((c.x << 12) + (c.y << 6) + c.z) * 2 + (c.w >> 5)], 1u << (c.w & 31));
}

// --------------------------------------------------------------- megakernel
// Block = 4x4x4 l2-voxels = 2x2x2 l3-voxels (aligned: conv2/conv3 stride-2
// windows never cross the block). h1 and h2 live only in LDS (h2 overlays h1
// after phase 2). Pooled sums go straight to s[b][128] via atomics.
__global__ __launch_bounds__(256, 4) void mega_k(
    const float* __restrict__ grid, const unsigned* __restrict__ bits,
    const unsigned* __restrict__ W1pk, const _Float16* __restrict__ W2hT,
    const _Float16* __restrict__ W3hT, float* __restrict__ s, float* __restrict__ cnt)
{
  __shared__ _Float16 gse[100 * 14];       // g(z) pairs at even z
  __shared__ _Float16 gso[100 * 14];       // g(z+1) pairs at even z
  __shared__ float    msk[512];            // [p][v2]
  __shared__ float    m2s[64];
  __shared__ float    m3s[8];
  __shared__ __align__(16) _Float16 h1f[4 * 8 * 64 * 8];  // 32 KB, B-frag order
  _Float16* const h2s = h1f;               // overlay: [v2 64][c pitch 88] f16

  const int tid = threadIdx.x;
  const int bid = blockIdx.x;
  const int b  = bid >> 9;
  const int X2 = (bid >> 6) & 7, Y2 = (bid >> 3) & 7, Z2 = bid & 7;
  const int gb = b << 18;
  const int gx0 = X2 * 8 - 1, gy0 = Y2 * 8 - 1, gz0 = Z2 * 8 - 1;

  // ---- phase 0: stage grid tile (f16 even/odd pair copies) + mask bits
  for (int e = tid; e < 1000; e += 256) {
    const int x = e / 100, r = e - x * 100, y = r / 10, z = r - y * 10;
    const int gx = gx0 + x, gy = gy0 + y, gz = gz0 + z;
    const bool ok = ((unsigned)gx < 64u) & ((unsigned)gy < 64u) & ((unsigned)gz < 64u);
    const float v = ok ? grid[gb + (gx << 12) + (gy << 6) + gz] : 0.f;
    const _Float16 h = (_Float16)v;
    const int rowb = (x * 10 + y) * 14;
    gse[rowb + z] = h;
    if (z >= 1) gso[rowb + z - 1] = h;
  }
  for (int e = tid; e < 512; e += 256) {
    const int x1 = e >> 6, y1 = (e >> 3) & 7, z1 = e & 7;
    const int gx = X2 * 8 + x1, gy = Y2 * 8 + y1, gz = Z2 * 8 + z1;
    const unsigned w = bits[(((b << 12) + (gx << 6) + gy) << 1) + (gz >> 5)];
    const float mv = ((w >> (gz & 31)) & 1u) ? 1.f : 0.f;
    const int p  = ((x1 & 1) << 2) | ((y1 & 1) << 1) | (z1 & 1);
    const int v2 = ((x1 >> 1) << 4) | ((y1 >> 1) << 2) | (z1 >> 1);
    msk[p * 64 + v2] = mv;
  }
  __syncthreads();

  const int lane = tid & 63;
  const int wid  = tid >> 6;

  if (wid == 0) {   // m2 = max over children
    float m = 0.f;
    #pragma unroll
    for (int p = 0; p < 8; ++p) m = fmaxf(m, msk[p * 64 + lane]);
    m2s[lane] = m;
  }

  // ---- phase 1: conv1 voxel-pair via pk_fma -> h1f (B-frag order)
  const int v2 = tid & 63;
  const int pq = tid >> 6;                   // pA = 2pq (pz=0), pB = 2pq+1
  {
    const int x2 = v2 >> 4, y2 = (v2 >> 2) & 3, z2 = v2 & 3;
    const int lx = 2*x2 + (pq >> 1), ly = 2*y2 + (pq & 1), lzz = 2*z2;

    f16x2 h1pk[32];
    #pragma unroll
    for (int c = 0; c < 32; ++c) { h1pk[c].x = (_Float16)0; h1pk[c].y = (_Float16)0; }

    #pragma unroll
    for (int tx = 0; tx < 3; ++tx) {
      #pragma unroll
      for (int ty = 0; ty < 3; ++ty) {
        const int rowb = ((lx + tx) * 10 + (ly + ty)) * 14;
        const f16x2 g0 = *reinterpret_cast<const f16x2*>(&gse[rowb + lzz]);
        const f16x2 g1 = *reinterpret_cast<const f16x2*>(&gso[rowb + lzz]);
        const f16x2 g2 = *reinterpret_cast<const f16x2*>(&gse[rowb + lzz + 2]);
        const unsigned* __restrict__ wb = &W1pk[((tx * 3 + ty) * 3) * 32];
        #pragma unroll
        for (int c = 0; c < 32; ++c) {
          h1pk[c] += g0 * __builtin_bit_cast(f16x2, wb[c]);
          h1pk[c] += g1 * __builtin_bit_cast(f16x2, wb[32 + c]);
          h1pk[c] += g2 * __builtin_bit_cast(f16x2, wb[64 + c]);
        }
      }
    }

    const float mA = msk[(2*pq) * 64 + v2], mB = msk[(2*pq + 1) * 64 + v2];
    f16x2 mk; mk.x = (_Float16)mA; mk.y = (_Float16)mB;
    const _Float16 z0 = (_Float16)0;
    #pragma unroll
    for (int c = 0; c < 32; ++c) {
      f16x2 v = h1pk[c];
      v.x = v.x > z0 ? v.x : z0;
      v.y = v.y > z0 ? v.y : z0;
      h1pk[c] = v * mk;
    }

    const int mt = v2 >> 4, r = v2 & 15;
    #pragma unroll
    for (int q = 0; q < 4; ++q) {
      f16x8 va, vb;
      #pragma unroll
      for (int j = 0; j < 8; ++j) { va[j] = h1pk[q*8 + j].x; vb[j] = h1pk[q*8 + j].y; }
      const int fl = r + 16 * q;
      *reinterpret_cast<f16x8*>(&h1f[(((mt*8 + 2*pq    ) * 64) + fl) * 8]) = va;
      *reinterpret_cast<f16x8*>(&h1f[(((mt*8 + 2*pq + 1) * 64) + fl) * 8]) = vb;
    }
  }
  __syncthreads();

  // ---- phase 2: conv2 MFMA. wave = 16-o-channel tile, D[o][v2], K=256
  const int l15 = lane & 15, l4 = lane >> 4;
  f32x4 acc[4];
  #pragma unroll
  for (int nt = 0; nt < 4; ++nt) acc[nt] = (f32x4){0.f, 0.f, 0.f, 0.f};

  const _Float16* __restrict__ w2b = W2hT + ((wid*16 + l15) * 256 + l4 * 8);
  #pragma unroll
  for (int ks = 0; ks < 8; ++ks) {
    const f16x8 af = *reinterpret_cast<const f16x8*>(w2b + ks * 32);
    #pragma unroll
    for (int nt = 0; nt < 4; ++nt) {
      const f16x8 bf = *reinterpret_cast<const f16x8*>(&h1f[((nt*8 + ks) * 64 + lane) * 8]);
      acc[nt] = __builtin_amdgcn_mfma_f32_16x16x32_f16(af, bf, acc[nt], 0, 0, 0);
    }
  }

  // epilogue -> registers (h1f still being read by other waves)
  const int o0 = wid * 16 + l4 * 4;
  uint2 hpack[4];
  #pragma unroll
  for (int nt = 0; nt < 4; ++nt) {
    const int v2l = nt * 16 + l15;
    const float m2v = m2s[v2l];
    const float d0 = fmaxf(acc[nt][0], 0.f) * m2v;
    const float d1 = fmaxf(acc[nt][1], 0.f) * m2v;
    const float d2 = fmaxf(acc[nt][2], 0.f) * m2v;
    const float d3 = fmaxf(acc[nt][3], 0.f) * m2v;
    f16x2 p0; p0.x = (_Float16)d0; p0.y = (_Float16)d1;
    f16x2 p1; p1.x = (_Float16)d2; p1.y = (_Float16)d3;
    hpack[nt].x = __builtin_bit_cast(unsigned, p0);
    hpack[nt].y = __builtin_bit_cast(unsigned, p1);
  }
  __syncthreads();                                // all h1f reads done

  #pragma unroll
  for (int nt = 0; nt < 4; ++nt) {
    const int v2l = nt * 16 + l15;
    *reinterpret_cast<uint2*>(&h2s[v2l * 88 + o0]) = hpack[nt];
  }
  if (tid < 8) {                                  // m3 = max over 8 children
    const int x3 = tid >> 2, y3 = (tid >> 1) & 1, z3 = tid & 1;
    float m = 0.f;
    #pragma unroll
    for (int p = 0; p < 8; ++p) {
      const int cv = (((2*x3 + (p>>2)) << 4) | ((2*y3 + ((p>>1)&1)) << 2) | (2*z3 + (p&1)));
      m = fmaxf(m, m2s[cv]);
    }
    m3s[tid] = m;
  }
  __syncthreads();

  // ---- phase 3: conv3 MFMA, D[o=128][v3=8(pad16)], K=512; pool -> atomics
  f32x4 c3[2];
  c3[0] = (f32x4){0.f,0.f,0.f,0.f};
  c3[1] = (f32x4){0.f,0.f,0.f,0.f};
  const int mbase = wid * 32;
  const int v3 = l15 & 7;
  const int x3 = v3 >> 2, y3 = (v3 >> 1) & 1, z3 = v3 & 1;
  const _Float16* __restrict__ a0b = W3hT + ((mbase      + l15) * 512 + l4 * 8);
  const _Float16* __restrict__ a1b = W3hT + ((mbase + 16 + l15) * 512 + l4 * 8);

  #pragma unroll
  for (int ks = 0; ks < 16; ++ks) {
    const int p = ks >> 1;
    const int vox = (((2*x3 + (p>>2)) << 4) | ((2*y3 + ((p>>1)&1)) << 2) | (2*z3 + (p&1)));
    const int c0 = (ks & 1) * 32 + l4 * 8;
    const f16x8 bf = *reinterpret_cast<const f16x8*>(&h2s[vox * 88 + c0]);
    const f16x8 a0 = *reinterpret_cast<const f16x8*>(a0b + ks * 32);
    const f16x8 a1 = *reinterpret_cast<const f16x8*>(a1b + ks * 32);
    c3[0] = __builtin_amdgcn_mfma_f32_16x16x32_f16(a0, bf, c3[0], 0, 0, 0);
    c3[1] = __builtin_amdgcn_mfma_f32_16x16x32_f16(a1, bf, c3[1], 0, 0, 0);
  }

  const float m3v = (l15 < 8) ? m3s[l15] : 0.f;
  float part[2][4];
  #pragma unroll
  for (int mt = 0; mt < 2; ++mt)
    #pragma unroll
    for (int j = 0; j < 4; ++j)
      part[mt][j] = fmaxf(c3[mt][j], 0.f) * m3v;
  #pragma unroll
  for (int d = 1; d < 16; d <<= 1) {
    #pragma unroll
    for (int mt = 0; mt < 2; ++mt)
      #pragma unroll
      for (int j = 0; j < 4; ++j)
        part[mt][j] += __shfl_xor(part[mt][j], d, 64);
  }
  if (l15 == 0) {
    #pragma unroll
    for (int mt = 0; mt < 2; ++mt)
      #pragma unroll
      for (int j = 0; j < 4; ++j)
        atomicAdd(&s[b * 128 + mbase + mt * 16 + l4 * 4 + j], part[mt][j]);
  }
  if (tid == 0) {
    float t = 0.f;
    #pragma unroll
    for (int i = 0; i < 8; ++i) t += m3s[i];
    atomicAdd(&cnt[b], t);
  }
}

// ---------------------------------------------------------------- final FC
__global__ __launch_bounds__(256) void fc_k(
    const float* __restrict__ s, const float* __restrict__ cnt,
    const float* __restrict__ fc_w, const float* __restrict__ fc_b,
    float* __restrict__ out)
{
  const int b = blockIdx.x, j = threadIdx.x;
  const float inv = 1.f / fmaxf(cnt[b], 1.f);
  float a = fc_b[j];
  #pragma unroll 8
  for (int c = 0; c < 128; ++c) a = fmaf(s[b * 128 + c] * inv, fc_w[c * 256 + j], a);
  out[b * 256 + j] = a;
}

// ---------------------------------------------------------------- launch
extern "C" void kernel_launch(void* const* d_in, const int* in_sizes, int n_in,
                              void* d_out, int out_size, void* d_ws, size_t ws_size,
                              hipStream_t stream)
{
  const int*   coords = (const int*)  d_in[0];
  const float* feats  = (const float*)d_in[1];
  const float* W1     = (const float*)d_in[2];
  const float* W2     = (const float*)d_in[3];
  const float* W3     = (const float*)d_in[4];
  const float* fc_w   = (const float*)d_in[5];
  const float* fc_b   = (const float*)d_in[6];
  float* out = (float*)d_out;
  const int N = in_sizes[0] / 4;

  float*    grid = (float*)d_ws;                 // 8.39 MB
  unsigned* bits = (unsigned*)(grid + GRID_ELEMS); // 256 KB (mask bitfield)
  float*    s    = (float*)(bits + 65536);       // 4 KB
  float*    cnt  = s + 1024;                     // 32 B
  unsigned* W1pk = (unsigned*)(cnt + 8);         // 3.5 KB
  _Float16* W2hT = (_Float16*)(W1pk + 864);      // 32 KB
  _Float16* W3hT = W2hT + 16384;                 // 128 KB
  // total ws use: ~8.9 MB

  hipMemsetAsync(grid, 0, (size_t)GRID_ELEMS * sizeof(float), stream);
  hipMemsetAsync(bits, 0, 65536*4 + 1024*4 + 32, stream);   // bits + s + cnt

  scatter_setup_k<<<324 + (N + 255) / 256, 256, 0, stream>>>(
      coords, feats, W1, W2, W3, grid, bits, W2hT, W3hT, W1pk, N);
  mega_k<<<4096, 256, 0, stream>>>(grid, bits, W1pk, W2hT, W3hT, s, cnt);
  fc_k  <<<8, 256, 0, stream>>>(s, cnt, fc_w, fc_b, out);
}

// Round 5
// 158.416 us; speedup vs baseline: 1.4537x; 1.4537x over previous
//
#include <hip/hip_runtime.h>
#include <hip/hip_bf16.h>

typedef __attribute__((ext_vector_type(2))) _Float16 f16x2;
typedef __attribute__((ext_vector_type(8))) _Float16 f16x8;
typedef __attribute__((ext_vector_type(4))) float    f32x4;

#define GRID_ELEMS (8*64*64*64)   // 2,097,152 voxels at level 0

// --------------------------------------------- scatter + weight-repack combo
// blocks [0,44): pre-fragment W2/W3 into per-lane MFMA A-frag order (uint4),
//                pack W1 as dup-f16 pairs.
// blocks [44,..): scatter points (atomicAdd grid, atomicOr mask bits).
__global__ __launch_bounds__(256) void scatter_setup_k(
    const int* __restrict__ coords, const float* __restrict__ feats,
    const float* __restrict__ W1, const float* __restrict__ W2, const float* __restrict__ W3,
    float* __restrict__ grid, unsigned* __restrict__ bits,
    uint4* __restrict__ W2f, uint4* __restrict__ W3fA, uint4* __restrict__ W3fB,
    unsigned* __restrict__ W1pk, int N)
{
  const int bi = blockIdx.x;
  if (bi < 44) {
    const int i = bi * 256 + threadIdx.x;
    if (i < 2048) {                       // W2f[(wid*8+ks)*64+lane]
      const int wid = i >> 9, ks = (i >> 6) & 7, lane = i & 63;
      const int l15 = lane & 15, l4 = lane >> 4, o = wid * 16 + l15;
      f16x8 v;
      #pragma unroll
      for (int j = 0; j < 8; ++j)          // k = ks*32 + l4*8 + j -> p=ks, c=l4*8+j
        v[j] = (_Float16)W2[ks * 2048 + (l4 * 8 + j) * 64 + o];
      W2f[i] = __builtin_bit_cast(uint4, v);
    } else if (i < 10240) {               // W3fA/B[(wid*16+ks)*64+lane]
      const int e = i - 2048, ab = e >> 12, r = e & 4095;
      const int wid = r >> 10, ks = (r >> 6) & 15, lane = r & 63;
      const int l15 = lane & 15, l4 = lane >> 4, o = wid * 32 + l15 + ab * 16;
      f16x8 v;
      #pragma unroll
      for (int j = 0; j < 8; ++j)          // k = ks*32+l4*8+j -> p=ks>>1, c=(ks&1)*32+l4*8+j
        v[j] = (_Float16)W3[(ks >> 1) * 8192 + ((ks & 1) * 32 + l4 * 8 + j) * 128 + o];
      (ab ? W3fB : W3fA)[r] = __builtin_bit_cast(uint4, v);
    } else if (i < 11104) {               // W1pk dup-f16
      const int t = i - 10240;
      _Float16 w = (_Float16)W1[t];
      f16x2 v; v.x = w; v.y = w;
      W1pk[t] = __builtin_bit_cast(unsigned, v);
    }
    return;
  }
  const int i = (bi - 44) * 256 + threadIdx.x;
  if (i >= N) return;
  const int4 c = reinterpret_cast<const int4*>(coords)[i];
  atomicAdd(&grid[((c.x * 64 + c.y) * 64 + c.z) * 64 + c.w], feats[i]);
  atomicOr(&bits[((c.x << 12) + (c.y << 6) + c.z) * 2 + (c.w >> 5)], 1u << (c.w & 31));
}

// --------------------------------------------------------------- megakernel
// Block = 8x8x8 l2-voxels (16^3 l1 region, 4^3 l3), processed as 8 sequential
// 4^3-l2 sub-tiles. W2/W3 A-frags live in registers for the whole block;
// grid-tile staging double-buffered; conv3 pooled sums accumulate in regs,
// one atomic batch per block.
__global__ __launch_bounds__(256, 2) void mega_k(
    const float* __restrict__ grid, const unsigned* __restrict__ bits,
    const unsigned* __restrict__ W1pk,
    const uint4* __restrict__ W2f, const uint4* __restrict__ W3fA,
    const uint4* __restrict__ W3fB,
    float* __restrict__ s, float* __restrict__ cnt)
{
  __shared__ _Float16 gse[2][1400];        // g(z) pairs at even z, dbuf
  __shared__ _Float16 gso[2][1400];        // g(z+1) pairs at even z, dbuf
  __shared__ _Float16 m1s[4096];           // l1 mask, [x1][y1][z1] 16^3
  __shared__ float    m2s[512];            // l2 mask, [x2][y2][z2] 8^3
  __shared__ float    m3s[64];             // l3 mask, [x3][y3][z3] 4^3
  __shared__ __align__(16) _Float16 h1f[16384];   // 32 KB, B-frag order
  _Float16* const h2s = h1f;               // overlay: [v2 64][c pitch 88]

  const int tid = threadIdx.x;
  const int bid = blockIdx.x;
  const int b  = bid >> 6;
  const int BX = (bid >> 4) & 3, BY = (bid >> 2) & 3, BZ = bid & 3;
  const int gb = b << 18;
  const int lane = tid & 63, wid = tid >> 6;
  const int l15 = lane & 15, l4 = lane >> 4;

  // ---- preload weight fragments into registers (coalesced; consumed later)
  uint4 w2f[8], w3a[16], w3b[16];
  #pragma unroll
  for (int ks = 0; ks < 8; ++ks) w2f[ks] = W2f[(wid * 8 + ks) * 64 + lane];
  #pragma unroll
  for (int ks = 0; ks < 16; ++ks) {
    w3a[ks] = W3fA[(wid * 16 + ks) * 64 + lane];
    w3b[ks] = W3fB[(wid * 16 + ks) * 64 + lane];
  }

  // ---- prologue: mask bits -> m1s ; grid tile t=0
  for (int e = tid; e < 4096; e += 256) {
    const int x1 = e >> 8, y1 = (e >> 4) & 15, z1 = e & 15;
    const int gx = BX * 16 + x1, gy = BY * 16 + y1, gz = BZ * 16 + z1;
    const unsigned w = bits[(((b << 12) + (gx << 6) + gy) << 1) + (gz >> 5)];
    m1s[e] = ((w >> (gz & 31)) & 1u) ? (_Float16)1 : (_Float16)0;
  }
  {
    const int gx0 = BX * 16 - 1, gy0 = BY * 16 - 1, gz0 = BZ * 16 - 1;
    for (int e = tid; e < 1000; e += 256) {
      const int x = e / 100, r = e - x * 100, y = r / 10, z = r - y * 10;
      const int gx = gx0 + x, gy = gy0 + y, gz = gz0 + z;
      const bool ok = ((unsigned)gx < 64u) & ((unsigned)gy < 64u) & ((unsigned)gz < 64u);
      const float v = ok ? grid[gb + (gx << 12) + (gy << 6) + gz] : 0.f;
      const _Float16 h = (_Float16)v;
      const int rowb = (x * 10 + y) * 14;
      gse[0][rowb + z] = h;
      if (z >= 1) gso[0][rowb + z - 1] = h;
    }
  }
  __syncthreads();
  for (int e = tid; e < 512; e += 256) {    // m2 = max over 8 l1 children
    const int x2 = e >> 6, y2 = (e >> 3) & 7, z2 = e & 7;
    float m = 0.f;
    #pragma unroll
    for (int p = 0; p < 8; ++p) {
      const int x1 = 2*x2 + (p >> 2), y1 = 2*y2 + ((p >> 1) & 1), z1 = 2*z2 + (p & 1);
      m = fmaxf(m, (float)m1s[(x1 * 16 + y1) * 16 + z1]);
    }
    m2s[e] = m;
  }
  __syncthreads();
  if (tid < 64) {                           // m3 = max over 8 l2 children
    const int x3 = tid >> 4, y3 = (tid >> 2) & 3, z3 = tid & 3;
    float m = 0.f;
    #pragma unroll
    for (int p = 0; p < 8; ++p)
      m = fmaxf(m, m2s[((2*x3 + (p>>2)) << 6) + ((2*y3 + ((p>>1)&1)) << 3) + (2*z3 + (p&1))]);
    m3s[tid] = m;
  }
  __syncthreads();

  float part[2][4];
  #pragma unroll
  for (int mt = 0; mt < 2; ++mt)
    #pragma unroll
    for (int j = 0; j < 4; ++j) part[mt][j] = 0.f;

  const int v2 = tid & 63;
  const int pq = tid >> 6;
  const int x2c = v2 >> 4, y2c = (v2 >> 2) & 3, z2c = v2 & 3;

  #pragma unroll 1
  for (int t = 0; t < 8; ++t) {
    const int cur = t & 1;
    const int Tx = t >> 2, Ty = (t >> 1) & 1, Tz = t & 1;

    // issue next sub-tile's grid loads (consumed after phase 1)
    float pre[4];
    if (t < 7) {
      const int nt_ = t + 1;
      const int nx0 = BX*16 + (nt_ >> 2)*8 - 1;
      const int ny0 = BY*16 + ((nt_ >> 1) & 1)*8 - 1;
      const int nz0 = BZ*16 + (nt_ & 1)*8 - 1;
      #pragma unroll
      for (int j = 0; j < 4; ++j) {
        const int e = tid + j * 256;
        float v = 0.f;
        if (e < 1000) {
          const int x = e / 100, r = e - x * 100, y = r / 10, z = r - y * 10;
          const int gx = nx0 + x, gy = ny0 + y, gz = nz0 + z;
          const bool ok = ((unsigned)gx < 64u) & ((unsigned)gy < 64u) & ((unsigned)gz < 64u);
          v = ok ? grid[gb + (gx << 12) + (gy << 6) + gz] : 0.f;
        }
        pre[j] = v;
      }
    }

    // ---- phase 1: conv1 voxel-pair via pk_fma -> h1f (B-frag order)
    {
      const int lx = 2*x2c + (pq >> 1), ly = 2*y2c + (pq & 1), lzz = 2*z2c;
      f16x2 h1pk[32];
      #pragma unroll
      for (int c = 0; c < 32; ++c) { h1pk[c].x = (_Float16)0; h1pk[c].y = (_Float16)0; }
      #pragma unroll
      for (int tx = 0; tx < 3; ++tx) {
        #pragma unroll
        for (int ty = 0; ty < 3; ++ty) {
          const int rowb = ((lx + tx) * 10 + (ly + ty)) * 14;
          const f16x2 g0 = *reinterpret_cast<const f16x2*>(&gse[cur][rowb + lzz]);
          const f16x2 g1 = *reinterpret_cast<const f16x2*>(&gso[cur][rowb + lzz]);
          const f16x2 g2 = *reinterpret_cast<const f16x2*>(&gse[cur][rowb + lzz + 2]);
          const unsigned* __restrict__ wb = &W1pk[((tx * 3 + ty) * 3) * 32];
          #pragma unroll
          for (int c = 0; c < 32; ++c) {
            h1pk[c] += g0 * __builtin_bit_cast(f16x2, wb[c]);
            h1pk[c] += g1 * __builtin_bit_cast(f16x2, wb[32 + c]);
            h1pk[c] += g2 * __builtin_bit_cast(f16x2, wb[64 + c]);
          }
        }
      }
      const f16x2 mk = *reinterpret_cast<const f16x2*>(
          &m1s[((Tx*8 + lx) * 16 + (Ty*8 + ly)) * 16 + (Tz*8 + lzz)]);
      const _Float16 z0 = (_Float16)0;
      #pragma unroll
      for (int c = 0; c < 32; ++c) {
        f16x2 v = h1pk[c];
        v.x = v.x > z0 ? v.x : z0;
        v.y = v.y > z0 ? v.y : z0;
        h1pk[c] = v * mk;
      }
      const int mt = v2 >> 4, r = v2 & 15;
      #pragma unroll
      for (int q = 0; q < 4; ++q) {
        f16x8 va, vb;
        #pragma unroll
        for (int j = 0; j < 8; ++j) { va[j] = h1pk[q*8 + j].x; vb[j] = h1pk[q*8 + j].y; }
        const int fl = r + 16 * q;
        *reinterpret_cast<f16x8*>(&h1f[(((mt*8 + 2*pq    ) * 64) + fl) * 8]) = va;
        *reinterpret_cast<f16x8*>(&h1f[(((mt*8 + 2*pq + 1) * 64) + fl) * 8]) = vb;
      }
    }

    // write next sub-tile's grid tile into the other buffer
    if (t < 7) {
      #pragma unroll
      for (int j = 0; j < 4; ++j) {
        const int e = tid + j * 256;
        if (e < 1000) {
          const int x = e / 100, r = e - x * 100, y = r / 10, z = r - y * 10;
          const _Float16 h = (_Float16)pre[j];
          const int rowb = (x * 10 + y) * 14;
          gse[cur ^ 1][rowb + z] = h;
          if (z >= 1) gso[cur ^ 1][rowb + z - 1] = h;
        }
      }
    }
    __syncthreads();                            // h1f ready, next tile ready

    // ---- phase 2: conv2 MFMA (A from regs), D[o][v2], K=256
    f32x4 acc[4];
    #pragma unroll
    for (int nt = 0; nt < 4; ++nt) acc[nt] = (f32x4){0.f, 0.f, 0.f, 0.f};
    #pragma unroll
    for (int ks = 0; ks < 8; ++ks) {
      const f16x8 af = __builtin_bit_cast(f16x8, w2f[ks]);
      #pragma unroll
      for (int nt = 0; nt < 4; ++nt) {
        const f16x8 bf = *reinterpret_cast<const f16x8*>(&h1f[((nt*8 + ks) * 64 + lane) * 8]);
        acc[nt] = __builtin_amdgcn_mfma_f32_16x16x32_f16(af, bf, acc[nt], 0, 0, 0);
      }
    }
    const int o0 = wid * 16 + l4 * 4;
    uint2 hpack[4];
    #pragma unroll
    for (int nt = 0; nt < 4; ++nt) {
      const int v2l = nt * 16 + l15;
      const float m2v = m2s[((Tx*4 + (v2l >> 4)) << 6) + ((Ty*4 + ((v2l >> 2) & 3)) << 3)
                            + (Tz*4 + (v2l & 3))];
      const float d0 = fmaxf(acc[nt][0], 0.f) * m2v;
      const float d1 = fmaxf(acc[nt][1], 0.f) * m2v;
      const float d2 = fmaxf(acc[nt][2], 0.f) * m2v;
      const float d3 = fmaxf(acc[nt][3], 0.f) * m2v;
      f16x2 p0; p0.x = (_Float16)d0; p0.y = (_Float16)d1;
      f16x2 p1; p1.x = (_Float16)d2; p1.y = (_Float16)d3;
      hpack[nt].x = __builtin_bit_cast(unsigned, p0);
      hpack[nt].y = __builtin_bit_cast(unsigned, p1);
    }
    __syncthreads();                            // h1f reads done
    #pragma unroll
    for (int nt = 0; nt < 4; ++nt)
      *reinterpret_cast<uint2*>(&h2s[(nt * 16 + l15) * 88 + o0]) = hpack[nt];
    __syncthreads();                            // h2s ready

    // ---- phase 3: conv3 MFMA (A from regs), octant's 8 l3-voxels, K=512
    f32x4 c3a = (f32x4){0.f,0.f,0.f,0.f};
    f32x4 c3b = (f32x4){0.f,0.f,0.f,0.f};
    const int v3 = l15 & 7;
    const int x3o = v3 >> 2, y3o = (v3 >> 1) & 1, z3o = v3 & 1;
    #pragma unroll
    for (int ks = 0; ks < 16; ++ks) {
      const int p = ks >> 1;
      const int vox = (((2*x3o + (p>>2)) << 4) | ((2*y3o + ((p>>1)&1)) << 2) | (2*z3o + (p&1)));
      const int c0 = (ks & 1) * 32 + l4 * 8;
      const f16x8 bf = *reinterpret_cast<const f16x8*>(&h2s[vox * 88 + c0]);
      c3a = __builtin_amdgcn_mfma_f32_16x16x32_f16(__builtin_bit_cast(f16x8, w3a[ks]), bf, c3a, 0, 0, 0);
      c3b = __builtin_amdgcn_mfma_f32_16x16x32_f16(__builtin_bit_cast(f16x8, w3b[ks]), bf, c3b, 0, 0, 0);
    }
    float m3v = 0.f;
    if (l15 < 8)
      m3v = m3s[((Tx*2 + x3o) << 4) + ((Ty*2 + y3o) << 2) + (Tz*2 + z3o)];
    #pragma unroll
    for (int j = 0; j < 4; ++j) {
      part[0][j] += fmaxf(c3a[j], 0.f) * m3v;
      part[1][j] += fmaxf(c3b[j], 0.f) * m3v;
    }
    __syncthreads();                            // h2s consumed (h1f reuse next t)
  }

  // ---- epilogue: reduce over the 16-lane groups, one atomic batch per block
  #pragma unroll
  for (int d = 1; d < 16; d <<= 1) {
    #pragma unroll
    for (int mt = 0; mt < 2; ++mt)
      #pragma unroll
      for (int j = 0; j < 4; ++j)
        part[mt][j] += __shfl_xor(part[mt][j], d, 64);
  }
  if (l15 == 0) {
    #pragma unroll
    for (int mt = 0; mt < 2; ++mt)
      #pragma unroll
      for (int j = 0; j < 4; ++j)
        atomicAdd(&s[b * 128 + wid * 32 + mt * 16 + l4 * 4 + j], part[mt][j]);
  }
  if (tid < 64) {
    float v = m3s[tid];
    #pragma unroll
    for (int d = 1; d < 64; d <<= 1) v += __shfl_xor(v, d, 64);
    if (tid == 0) atomicAdd(&cnt[b], v);
  }
}

// ---------------------------------------------------------------- final FC
__global__ __launch_bounds__(256) void fc_k(
    const float* __restrict__ s, const float* __restrict__ cnt,
    const float* __restrict__ fc_w, const float* __restrict__ fc_b,
    float* __restrict__ out)
{
  const int b = blockIdx.x, j = threadIdx.x;
  const float inv = 1.f / fmaxf(cnt[b], 1.f);
  float a = fc_b[j];
  #pragma unroll 8
  for (int c = 0; c < 128; ++c) a = fmaf(s[b * 128 + c] * inv, fc_w[c * 256 + j], a);
  out[b * 256 + j] = a;
}

// ---------------------------------------------------------------- launch
extern "C" void kernel_launch(void* const* d_in, const int* in_sizes, int n_in,
                              void* d_out, int out_size, void* d_ws, size_t ws_size,
                              hipStream_t stream)
{
  const int*   coords = (const int*)  d_in[0];
  const float* feats  = (const float*)d_in[1];
  const float* W1     = (const float*)d_in[2];
  const float* W2     = (const float*)d_in[3];
  const float* W3     = (const float*)d_in[4];
  const float* fc_w   = (const float*)d_in[5];
  const float* fc_b   = (const float*)d_in[6];
  float* out = (float*)d_out;
  const int N = in_sizes[0] / 4;

  float*    grid = (float*)d_ws;                    // 33.55 MB (floats)
  unsigned* bits = (unsigned*)(grid + GRID_ELEMS);  // 256 KB
  float*    s    = (float*)(bits + 65536);          // 4 KB
  float*    cnt  = s + 1024;                        // 32 B
  unsigned* W1pk = (unsigned*)(cnt + 8);            // 3456 B (16B-aligned end)
  uint4*    W2f  = (uint4*)(W1pk + 864);            // 32 KB
  uint4*    W3fA = W2f + 2048;                      // 64 KB
  uint4*    W3fB = W3fA + 4096;                     // 64 KB

  hipMemsetAsync(grid, 0, (size_t)GRID_ELEMS * sizeof(float), stream);
  hipMemsetAsync(bits, 0, 65536*4 + 1024*4 + 32, stream);   // bits + s + cnt

  scatter_setup_k<<<44 + (N + 255) / 256, 256, 0, stream>>>(
      coords, feats, W1, W2, W3, grid, bits, W2f, W3fA, W3fB, W1pk, N);
  mega_k<<<512, 256, 0, stream>>>(grid, bits, W1pk, W2f, W3fA, W3fB, s, cnt);
  fc_k  <<<8, 256, 0, stream>>>(s, cnt, fc_w, fc_b, out);
}

// Round 6
// 110.240 us; speedup vs baseline: 2.0890x; 1.4370x over previous
//
#include <hip/hip_runtime.h>
#include <hip/hip_bf16.h>

typedef __attribute__((ext_vector_type(2))) _Float16 f16x2;
typedef __attribute__((ext_vector_type(8))) _Float16 f16x8;
typedef __attribute__((ext_vector_type(4))) float    f32x4;

#define GRID_ELEMS (8*64*64*64)   // 2,097,152 voxels at level 0

// --------------------------------------------- scatter + weight-repack combo
// blocks [0,44): pre-fragment W2/W3 into per-lane MFMA A-frag order (uint4),
//                pack W1 as dup-f16 pairs.
// blocks [44,..): scatter points (atomicAdd grid, atomicOr mask bits).
__global__ __launch_bounds__(256) void scatter_setup_k(
    const int* __restrict__ coords, const float* __restrict__ feats,
    const float* __restrict__ W1, const float* __restrict__ W2, const float* __restrict__ W3,
    float* __restrict__ grid, unsigned* __restrict__ bits,
    uint4* __restrict__ W2f, uint4* __restrict__ W3fA, uint4* __restrict__ W3fB,
    unsigned* __restrict__ W1pk, int N)
{
  const int bi = blockIdx.x;
  if (bi < 44) {
    const int i = bi * 256 + threadIdx.x;
    if (i < 2048) {                       // W2f[(wid*8+ks)*64+lane]
      const int wid = i >> 9, ks = (i >> 6) & 7, lane = i & 63;
      const int l15 = lane & 15, l4 = lane >> 4, o = wid * 16 + l15;
      f16x8 v;
      #pragma unroll
      for (int j = 0; j < 8; ++j)          // k = ks*32 + l4*8 + j -> p=ks, c=l4*8+j
        v[j] = (_Float16)W2[ks * 2048 + (l4 * 8 + j) * 64 + o];
      W2f[i] = __builtin_bit_cast(uint4, v);
    } else if (i < 10240) {               // W3fA/B[(wid*16+ks)*64+lane]
      const int e = i - 2048, ab = e >> 12, r = e & 4095;
      const int wid = r >> 10, ks = (r >> 6) & 15, lane = r & 63;
      const int l15 = lane & 15, l4 = lane >> 4, o = wid * 32 + l15 + ab * 16;
      f16x8 v;
      #pragma unroll
      for (int j = 0; j < 8; ++j)          // k = ks*32+l4*8+j -> p=ks>>1, c=(ks&1)*32+l4*8+j
        v[j] = (_Float16)W3[(ks >> 1) * 8192 + ((ks & 1) * 32 + l4 * 8 + j) * 128 + o];
      (ab ? W3fB : W3fA)[r] = __builtin_bit_cast(uint4, v);
    } else if (i < 11104) {               // W1pk dup-f16
      const int t = i - 10240;
      _Float16 w = (_Float16)W1[t];
      f16x2 v; v.x = w; v.y = w;
      W1pk[t] = __builtin_bit_cast(unsigned, v);
    }
    return;
  }
  const int i = (bi - 44) * 256 + threadIdx.x;
  if (i >= N) return;
  const int4 c = reinterpret_cast<const int4*>(coords)[i];
  atomicAdd(&grid[((c.x * 64 + c.y) * 64 + c.z) * 64 + c.w], feats[i]);
  atomicOr(&bits[((c.x << 12) + (c.y << 6) + c.z) * 2 + (c.w >> 5)], 1u << (c.w & 31));
}

// --------------------------------------------------------------- megakernel
// Block = one octant: 4x4x4 l2-voxels (8^3 l1, 2^3 l3). 4096 blocks, 40.7KB
// LDS -> 4 blocks/CU. W2/W3 fragments streamed coalesced from L2 (prefetched
// across barriers / software-pipelined). Partial sums -> spart (no atomics).
__global__ __launch_bounds__(256, 4) void mega_k(
    const float* __restrict__ grid, const unsigned* __restrict__ bits,
    const unsigned* __restrict__ W1pk,
    const uint4* __restrict__ W2f, const uint4* __restrict__ W3fA,
    const uint4* __restrict__ W3fB,
    float* __restrict__ spart, float* __restrict__ cpart)
{
  __shared__ _Float16 gse[1400];           // g(z) pairs at even z
  __shared__ _Float16 gso[1400];           // g(z+1) pairs at even z
  __shared__ float    msk[512];            // [p][v2]
  __shared__ float    m2s[64];
  __shared__ float    m3s[8];
  __shared__ __align__(16) _Float16 h1f[16384];   // 32 KB, B-frag order
  _Float16* const h2s = h1f;               // overlay: [v2 64][c pitch 88]

  const int tid = threadIdx.x;
  const int bid = blockIdx.x;
  const int b  = bid >> 9;
  const int X2 = (bid >> 6) & 7, Y2 = (bid >> 3) & 7, Z2 = bid & 7;
  const int gb = b << 18;
  const int lane = tid & 63, wid = tid >> 6;
  const int l15 = lane & 15, l4 = lane >> 4;

  // ---- phase 0: stage grid tile + mask bits
  {
    const int gx0 = X2 * 8 - 1, gy0 = Y2 * 8 - 1, gz0 = Z2 * 8 - 1;
    for (int e = tid; e < 1000; e += 256) {
      const int x = e / 100, r = e - x * 100, y = r / 10, z = r - y * 10;
      const int gx = gx0 + x, gy = gy0 + y, gz = gz0 + z;
      const bool ok = ((unsigned)gx < 64u) & ((unsigned)gy < 64u) & ((unsigned)gz < 64u);
      const float v = ok ? grid[gb + (gx << 12) + (gy << 6) + gz] : 0.f;
      const _Float16 h = (_Float16)v;
      const int rowb = (x * 10 + y) * 14;
      gse[rowb + z] = h;
      if (z >= 1) gso[rowb + z - 1] = h;
    }
  }
  for (int e = tid; e < 512; e += 256) {
    const int x1 = e >> 6, y1 = (e >> 3) & 7, z1 = e & 7;
    const int gx = X2 * 8 + x1, gy = Y2 * 8 + y1, gz = Z2 * 8 + z1;
    const unsigned w = bits[(((b << 12) + (gx << 6) + gy) << 1) + (gz >> 5)];
    const float mv = ((w >> (gz & 31)) & 1u) ? 1.f : 0.f;
    const int p  = ((x1 & 1) << 2) | ((y1 & 1) << 1) | (z1 & 1);
    const int v2 = ((x1 >> 1) << 4) | ((y1 >> 1) << 2) | (z1 >> 1);
    msk[p * 64 + v2] = mv;
  }
  __syncthreads();

  if (wid == 0) {   // m2 = max over children
    float m = 0.f;
    #pragma unroll
    for (int p = 0; p < 8; ++p) m = fmaxf(m, msk[p * 64 + lane]);
    m2s[lane] = m;
  }

  // ---- prefetch W2 fragments (latency hides under phase 1 + barrier)
  uint4 w2r[8];
  #pragma unroll
  for (int ks = 0; ks < 8; ++ks) w2r[ks] = W2f[(wid * 8 + ks) * 64 + lane];

  // ---- phase 1: conv1 voxel-pair via pk_fma -> h1f (B-frag order)
  const int v2 = tid & 63;
  const int pq = tid >> 6;                   // pA = 2pq (pz=0), pB = 2pq+1
  {
    const int x2 = v2 >> 4, y2 = (v2 >> 2) & 3, z2 = v2 & 3;
    const int lx = 2*x2 + (pq >> 1), ly = 2*y2 + (pq & 1), lzz = 2*z2;

    f16x2 h1pk[32];
    #pragma unroll
    for (int c = 0; c < 32; ++c) { h1pk[c].x = (_Float16)0; h1pk[c].y = (_Float16)0; }

    #pragma unroll
    for (int tx = 0; tx < 3; ++tx) {
      #pragma unroll
      for (int ty = 0; ty < 3; ++ty) {
        const int rowb = ((lx + tx) * 10 + (ly + ty)) * 14;
        const f16x2 g0 = *reinterpret_cast<const f16x2*>(&gse[rowb + lzz]);
        const f16x2 g1 = *reinterpret_cast<const f16x2*>(&gso[rowb + lzz]);
        const f16x2 g2 = *reinterpret_cast<const f16x2*>(&gse[rowb + lzz + 2]);
        const unsigned* __restrict__ wb = &W1pk[((tx * 3 + ty) * 3) * 32];
        #pragma unroll
        for (int c = 0; c < 32; ++c) {
          h1pk[c] += g0 * __builtin_bit_cast(f16x2, wb[c]);
          h1pk[c] += g1 * __builtin_bit_cast(f16x2, wb[32 + c]);
          h1pk[c] += g2 * __builtin_bit_cast(f16x2, wb[64 + c]);
        }
      }
    }

    const float mA = msk[(2*pq) * 64 + v2], mB = msk[(2*pq + 1) * 64 + v2];
    f16x2 mk; mk.x = (_Float16)mA; mk.y = (_Float16)mB;
    const _Float16 z0 = (_Float16)0;
    #pragma unroll
    for (int c = 0; c < 32; ++c) {
      f16x2 v = h1pk[c];
      v.x = v.x > z0 ? v.x : z0;
      v.y = v.y > z0 ? v.y : z0;
      h1pk[c] = v * mk;
    }

    const int mt = v2 >> 4, r = v2 & 15;
    #pragma unroll
    for (int q = 0; q < 4; ++q) {
      f16x8 va, vb;
      #pragma unroll
      for (int j = 0; j < 8; ++j) { va[j] = h1pk[q*8 + j].x; vb[j] = h1pk[q*8 + j].y; }
      const int fl = r + 16 * q;
      *reinterpret_cast<f16x8*>(&h1f[(((mt*8 + 2*pq    ) * 64) + fl) * 8]) = va;
      *reinterpret_cast<f16x8*>(&h1f[(((mt*8 + 2*pq + 1) * 64) + fl) * 8]) = vb;
    }
  }
  __syncthreads();

  if (tid < 8) {                           // m3 = max over 8 l2 children
    const int x3 = tid >> 2, y3 = (tid >> 1) & 1, z3 = tid & 1;
    float m = 0.f;
    #pragma unroll
    for (int p = 0; p < 8; ++p) {
      const int cv = (((2*x3 + (p>>2)) << 4) | ((2*y3 + ((p>>1)&1)) << 2) | (2*z3 + (p&1)));
      m = fmaxf(m, m2s[cv]);
    }
    m3s[tid] = m;
  }

  // ---- phase 2: conv2 MFMA (A from prefetched regs), D[o][v2], K=256
  f32x4 acc[4];
  #pragma unroll
  for (int nt = 0; nt < 4; ++nt) acc[nt] = (f32x4){0.f, 0.f, 0.f, 0.f};
  #pragma unroll
  for (int ks = 0; ks < 8; ++ks) {
    const f16x8 af = __builtin_bit_cast(f16x8, w2r[ks]);
    #pragma unroll
    for (int nt = 0; nt < 4; ++nt) {
      const f16x8 bf = *reinterpret_cast<const f16x8*>(&h1f[((nt*8 + ks) * 64 + lane) * 8]);
      acc[nt] = __builtin_amdgcn_mfma_f32_16x16x32_f16(af, bf, acc[nt], 0, 0, 0);
    }
  }

  // prefetch W3 chunk 0 (4 K-steps) — latency hides under epilogue + barriers
  uint4 wa[4], wb2[4];
  #pragma unroll
  for (int j = 0; j < 4; ++j) {
    wa[j]  = W3fA[(wid * 16 + j) * 64 + lane];
    wb2[j] = W3fB[(wid * 16 + j) * 64 + lane];
  }

  // epilogue -> registers (h1f still being read by other waves)
  const int o0 = wid * 16 + l4 * 4;
  uint2 hpack[4];
  #pragma unroll
  for (int nt = 0; nt < 4; ++nt) {
    const int v2l = nt * 16 + l15;
    const float m2v = m2s[v2l];
    const float d0 = fmaxf(acc[nt][0], 0.f) * m2v;
    const float d1 = fmaxf(acc[nt][1], 0.f) * m2v;
    const float d2 = fmaxf(acc[nt][2], 0.f) * m2v;
    const float d3 = fmaxf(acc[nt][3], 0.f) * m2v;
    f16x2 p0; p0.x = (_Float16)d0; p0.y = (_Float16)d1;
    f16x2 p1; p1.x = (_Float16)d2; p1.y = (_Float16)d3;
    hpack[nt].x = __builtin_bit_cast(unsigned, p0);
    hpack[nt].y = __builtin_bit_cast(unsigned, p1);
  }
  __syncthreads();                                // all h1f reads done
  #pragma unroll
  for (int nt = 0; nt < 4; ++nt)
    *reinterpret_cast<uint2*>(&h2s[(nt * 16 + l15) * 88 + o0]) = hpack[nt];
  __syncthreads();                                // h2s ready

  // ---- phase 3: conv3 MFMA, software-pipelined W3-frag stream, K=512
  f32x4 c3a = (f32x4){0.f,0.f,0.f,0.f};
  f32x4 c3b = (f32x4){0.f,0.f,0.f,0.f};
  const int v3 = l15 & 7;
  const int x3o = v3 >> 2, y3o = (v3 >> 1) & 1, z3o = v3 & 1;

  #pragma unroll
  for (int kc = 0; kc < 4; ++kc) {
    uint4 na[4], nb[4];
    if (kc < 3) {
      #pragma unroll
      for (int j = 0; j < 4; ++j) {
        na[j] = W3fA[(wid * 16 + (kc + 1) * 4 + j) * 64 + lane];
        nb[j] = W3fB[(wid * 16 + (kc + 1) * 4 + j) * 64 + lane];
      }
    }
    #pragma unroll
    for (int j = 0; j < 4; ++j) {
      const int ks = kc * 4 + j;
      const int p = ks >> 1;
      const int vox = (((2*x3o + (p>>2)) << 4) | ((2*y3o + ((p>>1)&1)) << 2) | (2*z3o + (p&1)));
      const int c0 = (ks & 1) * 32 + l4 * 8;
      const f16x8 bf = *reinterpret_cast<const f16x8*>(&h2s[vox * 88 + c0]);
      c3a = __builtin_amdgcn_mfma_f32_16x16x32_f16(__builtin_bit_cast(f16x8, wa[j]),  bf, c3a, 0, 0, 0);
      c3b = __builtin_amdgcn_mfma_f32_16x16x32_f16(__builtin_bit_cast(f16x8, wb2[j]), bf, c3b, 0, 0, 0);
    }
    if (kc < 3) {
      #pragma unroll
      for (int j = 0; j < 4; ++j) { wa[j] = na[j]; wb2[j] = nb[j]; }
    }
  }

  // relu * m3 (zero for the duplicated N-half), reduce 16 lanes, store partials
  const float m3v = (l15 < 8) ? m3s[v3] : 0.f;
  float part[2][4];
  #pragma unroll
  for (int j = 0; j < 4; ++j) {
    part[0][j] = fmaxf(c3a[j], 0.f) * m3v;
    part[1][j] = fmaxf(c3b[j], 0.f) * m3v;
  }
  #pragma unroll
  for (int d = 1; d < 16; d <<= 1) {
    #pragma unroll
    for (int mt = 0; mt < 2; ++mt)
      #pragma unroll
      for (int j = 0; j < 4; ++j)
        part[mt][j] += __shfl_xor(part[mt][j], d, 64);
  }
  if (l15 == 0) {
    #pragma unroll
    for (int mt = 0; mt < 2; ++mt) {
      float4 t; t.x = part[mt][0]; t.y = part[mt][1]; t.z = part[mt][2]; t.w = part[mt][3];
      *reinterpret_cast<float4*>(&spart[(size_t)bid * 128 + wid * 32 + mt * 16 + l4 * 4]) = t;
    }
  }
  if (tid == 0) {
    float t = 0.f;
    #pragma unroll
    for (int i = 0; i < 8; ++i) t += m3s[i];
    cpart[bid] = t;
  }
}

// ------------------------------------------------- partial reduce + final FC
// block = batch b. Threads 0-127 sum spart channels; wave 2 sums cpart.
__global__ __launch_bounds__(256) void reduce_fc_k(
    const float* __restrict__ spart, const float* __restrict__ cpart,
    const float* __restrict__ fc_w, const float* __restrict__ fc_b,
    float* __restrict__ out)
{
  __shared__ float s_l[128];
  __shared__ float c_l;
  const int b = blockIdx.x, tid = threadIdx.x;
  if (tid < 128) {
    float a = 0.f;
    #pragma unroll 8
    for (int g = 0; g < 512; ++g) a += spart[(size_t)(b * 512 + g) * 128 + tid];
    s_l[tid] = a;
  } else if (tid < 192) {
    const int t = tid - 128;
    float a = 0.f;
    #pragma unroll
    for (int g = 0; g < 8; ++g) a += cpart[b * 512 + t * 8 + g];
    #pragma unroll
    for (int d = 1; d < 64; d <<= 1) a += __shfl_xor(a, d, 64);
    if (t == 0) c_l = a;
  }
  __syncthreads();
  const float inv = 1.f / fmaxf(c_l, 1.f);
  float o = fc_b[tid];
  #pragma unroll 8
  for (int c = 0; c < 128; ++c) o = fmaf(s_l[c] * inv, fc_w[c * 256 + tid], o);
  out[b * 256 + tid] = o;
}

// ---------------------------------------------------------------- launch
extern "C" void kernel_launch(void* const* d_in, const int* in_sizes, int n_in,
                              void* d_out, int out_size, void* d_ws, size_t ws_size,
                              hipStream_t stream)
{
  const int*   coords = (const int*)  d_in[0];
  const float* feats  = (const float*)d_in[1];
  const float* W1     = (const float*)d_in[2];
  const float* W2     = (const float*)d_in[3];
  const float* W3     = (const float*)d_in[4];
  const float* fc_w   = (const float*)d_in[5];
  const float* fc_b   = (const float*)d_in[6];
  float* out = (float*)d_out;
  const int N = in_sizes[0] / 4;

  float*    grid  = (float*)d_ws;                    // 8.39 MB
  unsigned* bits  = (unsigned*)(grid + GRID_ELEMS);  // 256 KB
  float*    spart = (float*)(bits + 65536);          // 2 MB (4096 x 128)
  float*    cpart = spart + 4096 * 128;              // 16 KB
  unsigned* W1pk  = (unsigned*)(cpart + 4096);       // 3456 B
  uint4*    W2f   = (uint4*)(W1pk + 864);            // 32 KB
  uint4*    W3fA  = W2f + 2048;                      // 64 KB
  uint4*    W3fB  = W3fA + 4096;                     // 64 KB
  // total ws use: ~10.8 MB

  // zero grid + bits in one shot (adjacent)
  hipMemsetAsync(grid, 0, (size_t)GRID_ELEMS * 4 + 65536 * 4, stream);

  scatter_setup_k<<<44 + (N + 255) / 256, 256, 0, stream>>>(
      coords, feats, W1, W2, W3, grid, bits, W2f, W3fA, W3fB, W1pk, N);
  mega_k<<<4096, 256, 0, stream>>>(grid, bits, W1pk, W2f, W3fA, W3fB, spart, cpart);
  reduce_fc_k<<<8, 256, 0, stream>>>(spart, cpart, fc_w, fc_b, out);
}

// Round 7
// 86.093 us; speedup vs baseline: 2.6749x; 1.2805x over previous
//
#include <hip/hip_runtime.h>
#include <hip/hip_bf16.h>

typedef __attribute__((ext_vector_type(2))) _Float16 f16x2;
typedef __attribute__((ext_vector_type(8))) _Float16 f16x8;
typedef __attribute__((ext_vector_type(4))) float    f32x4;

#define GRID_ELEMS (8*64*64*64)   // 2,097,152 voxels at level 0

// --------------------------------------------- scatter + weight-repack combo
// blocks [0,44): pre-fragment W1/W2/W3 into per-lane MFMA A-frag order.
// blocks [44,..): scatter points (atomicAdd grid, atomicOr mask bits).
__global__ __launch_bounds__(256) void scatter_setup_k(
    const int* __restrict__ coords, const float* __restrict__ feats,
    const float* __restrict__ W1, const float* __restrict__ W2, const float* __restrict__ W3,
    float* __restrict__ grid, unsigned* __restrict__ bits,
    uint4* __restrict__ W1f, uint4* __restrict__ W2f,
    uint4* __restrict__ W3fA, uint4* __restrict__ W3fB, int N)
{
  const int bi = blockIdx.x;
  if (bi < 44) {
    const int i = bi * 256 + threadIdx.x;
    if (i < 2048) {                       // W2f[(wid*8+ks)*64+lane]
      const int wid = i >> 9, ks = (i >> 6) & 7, lane = i & 63;
      const int l15 = lane & 15, l4 = lane >> 4, o = wid * 16 + l15;
      f16x8 v;
      #pragma unroll
      for (int j = 0; j < 8; ++j)          // k = ks*32 + l4*8 + j -> p=ks, c=l4*8+j
        v[j] = (_Float16)W2[ks * 2048 + (l4 * 8 + j) * 64 + o];
      W2f[i] = __builtin_bit_cast(uint4, v);
    } else if (i < 10240) {               // W3fA/B[(wid*16+ks)*64+lane]
      const int e = i - 2048, ab = e >> 12, r = e & 4095;
      const int wid = r >> 10, ks = (r >> 6) & 15, lane = r & 63;
      const int l15 = lane & 15, l4 = lane >> 4, o = wid * 32 + l15 + ab * 16;
      f16x8 v;
      #pragma unroll
      for (int j = 0; j < 8; ++j)          // k = ks*32+l4*8+j -> p=ks>>1, c=(ks&1)*32+l4*8+j
        v[j] = (_Float16)W3[(ks >> 1) * 8192 + ((ks & 1) * 32 + l4 * 8 + j) * 128 + o];
      (ab ? W3fB : W3fA)[r] = __builtin_bit_cast(uint4, v);
    } else if (i < 10368) {               // W1f[mt*64+lane]: A[m=ch][k=tap], k pad 27->32
      const int t = i - 10240;
      const int mt = t >> 6, l = t & 63;
      f16x8 v;
      #pragma unroll
      for (int j = 0; j < 8; ++j) {
        const int k = (l >> 4) * 8 + j;
        v[j] = (k < 27) ? (_Float16)W1[k * 32 + mt * 16 + (l & 15)] : (_Float16)0;
      }
      W1f[t] = __builtin_bit_cast(uint4, v);
    }
    return;
  }
  const int i = (bi - 44) * 256 + threadIdx.x;
  if (i >= N) return;
  const int4 c = reinterpret_cast<const int4*>(coords)[i];
  atomicAdd(&grid[((c.x * 64 + c.y) * 64 + c.z) * 64 + c.w], feats[i]);
  atomicOr(&bits[((c.x << 12) + (c.y << 6) + c.z) * 2 + (c.w >> 5)], 1u << (c.w & 31));
}

// --------------------------------------------------------------- megakernel
// Block = one octant: 4x4x4 l2-voxels (8^3 l1, 2^3 l3). All three convs on
// MFMA. conv1: A=W1 frags (regs), B gathered from LDS tile via tap-offset
// table, D written directly in conv2 B-frag order. conv2/conv3 as before.
// Pooled sums -> 64-bucket atomics.
__global__ __launch_bounds__(256, 4) void mega_k(
    const float* __restrict__ grid, const unsigned* __restrict__ bits,
    const uint4* __restrict__ W1f, const uint4* __restrict__ W2f,
    const uint4* __restrict__ W3fA, const uint4* __restrict__ W3fB,
    float* __restrict__ spart, float* __restrict__ cntB)
{
  __shared__ _Float16 tile[1008];          // dense [x][y][z] 10x10x10 f16
  __shared__ float    m1v[512];            // l1 mask by linear v1=(x1*8+y1)*8+z1
  __shared__ unsigned short toff[32];      // tap byte-offsets (pad k>=27 -> 0)
  __shared__ float    m2s[64];
  __shared__ float    m3s[8];
  __shared__ __align__(16) _Float16 h1f[16384];   // 32 KB, conv2 B-frag order
  _Float16* const h2s = h1f;               // overlay: [v2 64][c pitch 88]

  const int tid = threadIdx.x;
  const int bid = blockIdx.x;
  const int b  = bid >> 9;
  const int X2 = (bid >> 6) & 7, Y2 = (bid >> 3) & 7, Z2 = bid & 7;
  const int gb = b << 18;
  const int lane = tid & 63, wid = tid >> 6;
  const int l15 = lane & 15, l4 = lane >> 4;

  // ---- phase 0: stage grid tile + mask + tap table
  {
    const int gx0 = X2 * 8 - 1, gy0 = Y2 * 8 - 1, gz0 = Z2 * 8 - 1;
    for (int e = tid; e < 1000; e += 256) {
      const int x = e / 100, r = e - x * 100, y = r / 10, z = r - y * 10;
      const int gx = gx0 + x, gy = gy0 + y, gz = gz0 + z;
      const bool ok = ((unsigned)gx < 64u) & ((unsigned)gy < 64u) & ((unsigned)gz < 64u);
      tile[e] = (_Float16)(ok ? grid[gb + (gx << 12) + (gy << 6) + gz] : 0.f);
    }
  }
  for (int e = tid; e < 512; e += 256) {
    const int x1 = e >> 6, y1 = (e >> 3) & 7, z1 = e & 7;
    const int gx = X2 * 8 + x1, gy = Y2 * 8 + y1, gz = Z2 * 8 + z1;
    const unsigned w = bits[(((b << 12) + (gx << 6) + gy) << 1) + (gz >> 5)];
    m1v[e] = ((w >> (gz & 31)) & 1u) ? 1.f : 0.f;
  }
  if (tid < 32) {
    unsigned short off = 0;
    if (tid < 27) {
      const int tx = tid / 9, rr = tid - tx * 9, ty = rr / 3, tz = rr - ty * 3;
      off = (unsigned short)((tx * 100 + ty * 10 + tz) * 2);
    }
    toff[tid] = off;
  }

  // W-frag preloads (global, latency hidden under phase 0/1)
  const uint4 w1a = W1f[lane];
  const uint4 w1b = W1f[64 + lane];
  uint4 w2r[8];
  #pragma unroll
  for (int ks = 0; ks < 8; ++ks) w2r[ks] = W2f[(wid * 8 + ks) * 64 + lane];

  __syncthreads();

  if (wid == 0) {   // m2 = max over 8 l1 children
    const int v2 = lane;
    const int base = ((v2 >> 4) << 7) + (((v2 >> 2) & 3) << 4) + ((v2 & 3) << 1);
    float m = m1v[base];
    m = fmaxf(m, m1v[base + 1]);  m = fmaxf(m, m1v[base + 8]);
    m = fmaxf(m, m1v[base + 9]);  m = fmaxf(m, m1v[base + 64]);
    m = fmaxf(m, m1v[base + 65]); m = fmaxf(m, m1v[base + 72]);
    m = fmaxf(m, m1v[base + 73]);
    m2s[v2] = m;
  }

  int t_off[8];
  #pragma unroll
  for (int j = 0; j < 8; ++j) t_off[j] = toff[l4 * 8 + j];

  // ---- phase 1: conv1 MFMA. Per group of 16 voxels: gather B-frag from
  // tile, 2 MFMA (ch 0-15 / 16-31), relu*mask epilogue -> h1f (B-frag order).
  const char* tilec = reinterpret_cast<const char*>(tile);
  #pragma unroll
  for (int gi = 0; gi < 8; ++gi) {
    const int v1 = (wid * 8 + gi) * 16 + l15;
    const int x1 = v1 >> 6, y1 = (v1 >> 3) & 7, z1 = v1 & 7;
    const int base2 = (x1 * 100 + y1 * 10 + z1) * 2;
    f16x8 bf;
    #pragma unroll
    for (int j = 0; j < 8; ++j)
      bf[j] = *reinterpret_cast<const _Float16*>(tilec + base2 + t_off[j]);
    f32x4 aA = (f32x4){0.f, 0.f, 0.f, 0.f};
    f32x4 aB = (f32x4){0.f, 0.f, 0.f, 0.f};
    aA = __builtin_amdgcn_mfma_f32_16x16x32_f16(__builtin_bit_cast(f16x8, w1a), bf, aA, 0, 0, 0);
    aB = __builtin_amdgcn_mfma_f32_16x16x32_f16(__builtin_bit_cast(f16x8, w1b), bf, aB, 0, 0, 0);

    // epilogue: relu*mask (packed), write into conv2 B-frag slots
    const int p   = ((x1 & 1) << 2) | ((y1 & 1) << 1) | (z1 & 1);
    const int v2  = ((x1 >> 1) << 4) | ((y1 >> 1) << 2) | (z1 >> 1);
    const float mk = m1v[v1];
    f16x2 mk2; mk2.x = (_Float16)mk; mk2.y = (_Float16)mk;
    const _Float16 z0 = (_Float16)0;
    const int fbase = (((v2 >> 4) * 8 + p) * 64 + (v2 & 15)) * 8 + (l4 & 1) * 4;
    const int qsel = l4 >> 1;
    uint2 wA, wB;
    {
      f16x2 t0; t0.x = (_Float16)aA[0]; t0.y = (_Float16)aA[1];
      f16x2 t1; t1.x = (_Float16)aA[2]; t1.y = (_Float16)aA[3];
      t0.x = t0.x > z0 ? t0.x : z0; t0.y = t0.y > z0 ? t0.y : z0;
      t1.x = t1.x > z0 ? t1.x : z0; t1.y = t1.y > z0 ? t1.y : z0;
      t0 = t0 * mk2; t1 = t1 * mk2;
      wA.x = __builtin_bit_cast(unsigned, t0); wA.y = __builtin_bit_cast(unsigned, t1);
    }
    {
      f16x2 t0; t0.x = (_Float16)aB[0]; t0.y = (_Float16)aB[1];
      f16x2 t1; t1.x = (_Float16)aB[2]; t1.y = (_Float16)aB[3];
      t0.x = t0.x > z0 ? t0.x : z0; t0.y = t0.y > z0 ? t0.y : z0;
      t1.x = t1.x > z0 ? t1.x : z0; t1.y = t1.y > z0 ? t1.y : z0;
      t0 = t0 * mk2; t1 = t1 * mk2;
      wB.x = __builtin_bit_cast(unsigned, t0); wB.y = __builtin_bit_cast(unsigned, t1);
    }
    *reinterpret_cast<uint2*>(&h1f[fbase + qsel * 128])       = wA;   // ch 0-15
    *reinterpret_cast<uint2*>(&h1f[fbase + (2 + qsel) * 128]) = wB;   // ch 16-31
  }
  __syncthreads();

  if (tid < 8) {                           // m3 = max over 8 l2 children
    const int x3 = tid >> 2, y3 = (tid >> 1) & 1, z3 = tid & 1;
    float m = 0.f;
    #pragma unroll
    for (int p = 0; p < 8; ++p) {
      const int cv = (((2*x3 + (p>>2)) << 4) | ((2*y3 + ((p>>1)&1)) << 2) | (2*z3 + (p&1)));
      m = fmaxf(m, m2s[cv]);
    }
    m3s[tid] = m;
  }

  // ---- phase 2: conv2 MFMA (A from prefetched regs), D[o][v2], K=256
  f32x4 acc[4];
  #pragma unroll
  for (int nt = 0; nt < 4; ++nt) acc[nt] = (f32x4){0.f, 0.f, 0.f, 0.f};
  #pragma unroll
  for (int ks = 0; ks < 8; ++ks) {
    const f16x8 af = __builtin_bit_cast(f16x8, w2r[ks]);
    #pragma unroll
    for (int nt = 0; nt < 4; ++nt) {
      const f16x8 bf = *reinterpret_cast<const f16x8*>(&h1f[((nt*8 + ks) * 64 + lane) * 8]);
      acc[nt] = __builtin_amdgcn_mfma_f32_16x16x32_f16(af, bf, acc[nt], 0, 0, 0);
    }
  }

  // prefetch W3 chunk 0 (4 K-steps)
  uint4 wa[4], wb2[4];
  #pragma unroll
  for (int j = 0; j < 4; ++j) {
    wa[j]  = W3fA[(wid * 16 + j) * 64 + lane];
    wb2[j] = W3fB[(wid * 16 + j) * 64 + lane];
  }

  // epilogue -> registers (h1f still being read by other waves)
  const int o0 = wid * 16 + l4 * 4;
  uint2 hpack[4];
  #pragma unroll
  for (int nt = 0; nt < 4; ++nt) {
    const int v2l = nt * 16 + l15;
    const float m2v = m2s[v2l];
    const float d0 = fmaxf(acc[nt][0], 0.f) * m2v;
    const float d1 = fmaxf(acc[nt][1], 0.f) * m2v;
    const float d2 = fmaxf(acc[nt][2], 0.f) * m2v;
    const float d3 = fmaxf(acc[nt][3], 0.f) * m2v;
    f16x2 p0; p0.x = (_Float16)d0; p0.y = (_Float16)d1;
    f16x2 p1; p1.x = (_Float16)d2; p1.y = (_Float16)d3;
    hpack[nt].x = __builtin_bit_cast(unsigned, p0);
    hpack[nt].y = __builtin_bit_cast(unsigned, p1);
  }
  __syncthreads();                                // all h1f reads done
  #pragma unroll
  for (int nt = 0; nt < 4; ++nt)
    *reinterpret_cast<uint2*>(&h2s[(nt * 16 + l15) * 88 + o0]) = hpack[nt];
  __syncthreads();                                // h2s ready

  // ---- phase 3: conv3 MFMA, software-pipelined W3-frag stream, K=512
  f32x4 c3a = (f32x4){0.f,0.f,0.f,0.f};
  f32x4 c3b = (f32x4){0.f,0.f,0.f,0.f};
  const int v3 = l15 & 7;
  const int x3o = v3 >> 2, y3o = (v3 >> 1) & 1, z3o = v3 & 1;

  #pragma unroll
  for (int kc = 0; kc < 4; ++kc) {
    uint4 na[4], nb[4];
    if (kc < 3) {
      #pragma unroll
      for (int j = 0; j < 4; ++j) {
        na[j] = W3fA[(wid * 16 + (kc + 1) * 4 + j) * 64 + lane];
        nb[j] = W3fB[(wid * 16 + (kc + 1) * 4 + j) * 64 + lane];
      }
    }
    #pragma unroll
    for (int j = 0; j < 4; ++j) {
      const int ks = kc * 4 + j;
      const int p = ks >> 1;
      const int vox = (((2*x3o + (p>>2)) << 4) | ((2*y3o + ((p>>1)&1)) << 2) | (2*z3o + (p&1)));
      const int c0 = (ks & 1) * 32 + l4 * 8;
      const f16x8 bf = *reinterpret_cast<const f16x8*>(&h2s[vox * 88 + c0]);
      c3a = __builtin_amdgcn_mfma_f32_16x16x32_f16(__builtin_bit_cast(f16x8, wa[j]),  bf, c3a, 0, 0, 0);
      c3b = __builtin_amdgcn_mfma_f32_16x16x32_f16(__builtin_bit_cast(f16x8, wb2[j]), bf, c3b, 0, 0, 0);
    }
    if (kc < 3) {
      #pragma unroll
      for (int j = 0; j < 4; ++j) { wa[j] = na[j]; wb2[j] = nb[j]; }
    }
  }

  // relu * m3 (zero for duplicated N-half), reduce 16 lanes, bucket atomics
  const float m3v = (l15 < 8) ? m3s[v3] : 0.f;
  float part[2][4];
  #pragma unroll
  for (int j = 0; j < 4; ++j) {
    part[0][j] = fmaxf(c3a[j], 0.f) * m3v;
    part[1][j] = fmaxf(c3b[j], 0.f) * m3v;
  }
  #pragma unroll
  for (int d = 1; d < 16; d <<= 1) {
    #pragma unroll
    for (int mt = 0; mt < 2; ++mt)
      #pragma unroll
      for (int j = 0; j < 4; ++j)
        part[mt][j] += __shfl_xor(part[mt][j], d, 64);
  }
  if (l15 == 0) {
    const int sb = (b * 64 + (bid & 63)) * 128 + wid * 32;
    #pragma unroll
    for (int mt = 0; mt < 2; ++mt)
      #pragma unroll
      for (int j = 0; j < 4; ++j)
        atomicAdd(&spart[sb + mt * 16 + l4 * 4 + j], part[mt][j]);
  }
  if (tid == 0) {
    float t = 0.f;
    #pragma unroll
    for (int i = 0; i < 8; ++i) t += m3s[i];
    atomicAdd(&cntB[b * 64 + (bid & 63)], t);
  }
}

// ------------------------------------------------- bucket reduce + final FC
__global__ __launch_bounds__(256) void reduce_fc_k(
    const float* __restrict__ spart, const float* __restrict__ cntB,
    const float* __restrict__ fc_w, const float* __restrict__ fc_b,
    float* __restrict__ out)
{
  __shared__ float s_l[128];
  __shared__ float c_l;
  const int b = blockIdx.x, tid = threadIdx.x;
  if (tid < 128) {
    float a = 0.f;
    #pragma unroll 8
    for (int g = 0; g < 64; ++g) a += spart[(b * 64 + g) * 128 + tid];
    s_l[tid] = a;
  } else if (tid < 192) {
    float a = cntB[b * 64 + (tid - 128)];
    #pragma unroll
    for (int d = 1; d < 64; d <<= 1) a += __shfl_xor(a, d, 64);
    if (tid == 128) c_l = a;
  }
  __syncthreads();
  const float inv = 1.f / fmaxf(c_l, 1.f);
  float o = fc_b[tid];
  #pragma unroll 8
  for (int c = 0; c < 128; ++c) o = fmaf(s_l[c] * inv, fc_w[c * 256 + tid], o);
  out[b * 256 + tid] = o;
}

// ---------------------------------------------------------------- launch
extern "C" void kernel_launch(void* const* d_in, const int* in_sizes, int n_in,
                              void* d_out, int out_size, void* d_ws, size_t ws_size,
                              hipStream_t stream)
{
  const int*   coords = (const int*)  d_in[0];
  const float* feats  = (const float*)d_in[1];
  const float* W1     = (const float*)d_in[2];
  const float* W2     = (const float*)d_in[3];
  const float* W3     = (const float*)d_in[4];
  const float* fc_w   = (const float*)d_in[5];
  const float* fc_b   = (const float*)d_in[6];
  float* out = (float*)d_out;
  const int N = in_sizes[0] / 4;

  float*    grid  = (float*)d_ws;                    // 8.39 MB
  unsigned* bits  = (unsigned*)(grid + GRID_ELEMS);  // 256 KB
  float*    spart = (float*)(bits + 65536);          // 256 KB (8 x 64 x 128)
  float*    cntB  = spart + 8 * 64 * 128;            // 2 KB
  uint4*    W1f   = (uint4*)(cntB + 512);            // 2 KB (128 uint4)
  uint4*    W2f   = W1f + 128;                       // 32 KB
  uint4*    W3fA  = W2f + 2048;                      // 64 KB
  uint4*    W3fB  = W3fA + 4096;                     // 64 KB
  // total ws use: ~9.1 MB

  // zero grid + bits + spart + cntB in one shot (contiguous)
  hipMemsetAsync(grid, 0, (size_t)GRID_ELEMS * 4 + 65536 * 4 + 65536 * 4 + 512 * 4, stream);

  scatter_setup_k<<<44 + (N + 255) / 256, 256, 0, stream>>>(
      coords, feats, W1, W2, W3, grid, bits, W1f, W2f, W3fA, W3fB, N);
  mega_k<<<4096, 256, 0, stream>>>(grid, bits, W1f, W2f, W3fA, W3fB, spart, cntB);
  reduce_fc_k<<<8, 256, 0, stream>>>(spart, cntB, fc_w, fc_b, out);
}

// Round 8
// 74.737 us; speedup vs baseline: 3.0814x; 1.1519x over previous
//
#include <hip/hip_runtime.h>
#include <hip/hip_bf16.h>
#include <hip/hip_fp16.h>

typedef __attribute__((ext_vector_type(2))) _Float16 f16x2;
typedef __attribute__((ext_vector_type(8))) _Float16 f16x8;
typedef __attribute__((ext_vector_type(4))) float    f32x4;

#define GRID_ELEMS (8*64*64*64)   // 2,097,152 voxels at level 0

// --------------------------------------------- scatter + weight-repack combo
// blocks [0,44): pre-fragment W1/W2/W3 into per-lane MFMA A-frag order.
// blocks [44,..): scatter points — ONE packed-f16 atomic adds (feat, 1.0)
// into grid_pk[voxel] = {lo: f16 value-sum, hi: f16 point-count}.
__global__ __launch_bounds__(256) void scatter_setup_k(
    const int* __restrict__ coords, const float* __restrict__ feats,
    const float* __restrict__ W1, const float* __restrict__ W2, const float* __restrict__ W3,
    __half2* __restrict__ gpk,
    uint4* __restrict__ W1f, uint4* __restrict__ W2f,
    uint4* __restrict__ W3fA, uint4* __restrict__ W3fB, int N)
{
  const int bi = blockIdx.x;
  if (bi < 44) {
    const int i = bi * 256 + threadIdx.x;
    if (i < 2048) {                       // W2f[(wid*8+ks)*64+lane]
      const int wid = i >> 9, ks = (i >> 6) & 7, lane = i & 63;
      const int l15 = lane & 15, l4 = lane >> 4, o = wid * 16 + l15;
      f16x8 v;
      #pragma unroll
      for (int j = 0; j < 8; ++j)          // k = ks*32 + l4*8 + j -> p=ks, c=l4*8+j
        v[j] = (_Float16)W2[ks * 2048 + (l4 * 8 + j) * 64 + o];
      W2f[i] = __builtin_bit_cast(uint4, v);
    } else if (i < 10240) {               // W3fA/B[(wid*16+ks)*64+lane]
      const int e = i - 2048, ab = e >> 12, r = e & 4095;
      const int wid = r >> 10, ks = (r >> 6) & 15, lane = r & 63;
      const int l15 = lane & 15, l4 = lane >> 4, o = wid * 32 + l15 + ab * 16;
      f16x8 v;
      #pragma unroll
      for (int j = 0; j < 8; ++j)          // k = ks*32+l4*8+j -> p=ks>>1, c=(ks&1)*32+l4*8+j
        v[j] = (_Float16)W3[(ks >> 1) * 8192 + ((ks & 1) * 32 + l4 * 8 + j) * 128 + o];
      (ab ? W3fB : W3fA)[r] = __builtin_bit_cast(uint4, v);
    } else if (i < 10368) {               // W1f[mt*64+lane]: A[m=ch][k=tap], k pad 27->32
      const int t = i - 10240;
      const int mt = t >> 6, l = t & 63;
      f16x8 v;
      #pragma unroll
      for (int j = 0; j < 8; ++j) {
        const int k = (l >> 4) * 8 + j;
        v[j] = (k < 27) ? (_Float16)W1[k * 32 + mt * 16 + (l & 15)] : (_Float16)0;
      }
      W1f[t] = __builtin_bit_cast(uint4, v);
    }
    return;
  }
  const int i = (bi - 44) * 256 + threadIdx.x;
  if (i >= N) return;
  const int4 c = reinterpret_cast<const int4*>(coords)[i];
  const int idx = ((c.x * 64 + c.y) * 64 + c.z) * 64 + c.w;
  const __half2 v = __halves2half2(__float2half_rn(feats[i]), __float2half_rn(1.0f));
  unsafeAtomicAdd(&gpk[idx], v);         // global_atomic_pk_add_f16
}

// --------------------------------------------------------------- megakernel
// Block = one octant: 4x4x4 l2-voxels (8^3 l1, 2^3 l3). All three convs on
// MFMA. conv1+conv2 K-chunked in 2 halves (even-x / odd-x l1 voxels) so h1f
// is 16 KB -> ~20.7 KB LDS -> 6-7 blocks/CU. W3 frags streamed from L2,
// software-pipelined. Pooled sums -> 64-bucket atomics.
__global__ __launch_bounds__(256, 6) void mega_k(
    const unsigned* __restrict__ gpk,
    const uint4* __restrict__ W1f, const uint4* __restrict__ W2f,
    const uint4* __restrict__ W3fA, const uint4* __restrict__ W3fB,
    float* __restrict__ spart, float* __restrict__ cntB)
{
  __shared__ unsigned short tile[1008];    // dense [x][y][z] 10x10x10, f16 bits
  __shared__ float    m1v[512];            // l1 mask, v1=(x1*8+y1)*8+z1
  __shared__ unsigned short toff[32];      // tap byte-offsets (pad k>=27 -> 0)
  __shared__ float    m2s[64];
  __shared__ float    m3s[8];
  __shared__ __align__(16) _Float16 h1f[8192];   // 16 KB, conv2 B-frag order (K-half)
  _Float16* const h2s = h1f;               // overlay after conv2: [v2 64][c pitch 88]

  const int tid = threadIdx.x;
  const int bid = blockIdx.x;
  const int b  = bid >> 9;
  const int X2 = (bid >> 6) & 7, Y2 = (bid >> 3) & 7, Z2 = bid & 7;
  const int gb = b << 18;
  const int lane = tid & 63, wid = tid >> 6;
  const int l15 = lane & 15, l4 = lane >> 4;

  // ---- phase 0: stage grid tile (f16 val) + derive l1 mask from cnt half
  {
    const int gx0 = X2 * 8 - 1, gy0 = Y2 * 8 - 1, gz0 = Z2 * 8 - 1;
    for (int e = tid; e < 1000; e += 256) {
      const int x = e / 100, r = e - x * 100, y = r / 10, z = r - y * 10;
      const int gx = gx0 + x, gy = gy0 + y, gz = gz0 + z;
      const bool ok = ((unsigned)gx < 64u) & ((unsigned)gy < 64u) & ((unsigned)gz < 64u);
      const unsigned g = ok ? gpk[gb + (gx << 12) + (gy << 6) + gz] : 0u;
      tile[e] = (unsigned short)(g & 0xffffu);
      const int ix = x - 1, iy = y - 1, iz = z - 1;
      if (((unsigned)ix < 8u) & ((unsigned)iy < 8u) & ((unsigned)iz < 8u))
        m1v[(ix << 6) + (iy << 3) + iz] = (g >> 16) ? 1.f : 0.f;
    }
  }
  if (tid < 32) {
    unsigned short off = 0;
    if (tid < 27) {
      const int tx = tid / 9, rr = tid - tx * 9, ty = rr / 3, tz = rr - ty * 3;
      off = (unsigned short)((tx * 100 + ty * 10 + tz) * 2);
    }
    toff[tid] = off;
  }

  // W-frag preloads (global/L2, latency hidden under phase 0/1)
  const uint4 w1a = W1f[lane];
  const uint4 w1b = W1f[64 + lane];
  uint4 w2r[8];
  #pragma unroll
  for (int ks = 0; ks < 8; ++ks) w2r[ks] = W2f[(wid * 8 + ks) * 64 + lane];

  __syncthreads();

  if (wid == 0) {   // m2 = max over 8 l1 children
    const int v2 = lane;
    const int base = ((v2 >> 4) << 7) + (((v2 >> 2) & 3) << 4) + ((v2 & 3) << 1);
    float m = m1v[base];
    m = fmaxf(m, m1v[base + 1]);  m = fmaxf(m, m1v[base + 8]);
    m = fmaxf(m, m1v[base + 9]);  m = fmaxf(m, m1v[base + 64]);
    m = fmaxf(m, m1v[base + 65]); m = fmaxf(m, m1v[base + 72]);
    m = fmaxf(m, m1v[base + 73]);
    m2s[v2] = m;
  }

  int t_off[8];
  #pragma unroll
  for (int j = 0; j < 8; ++j) t_off[j] = toff[l4 * 8 + j];

  const char* tilec = reinterpret_cast<const char*>(tile);
  f32x4 acc[4];
  #pragma unroll
  for (int nt = 0; nt < 4; ++nt) acc[nt] = (f32x4){0.f, 0.f, 0.f, 0.f};

  // ---- phases 1+2, K-chunked: chunk c covers l1 voxels with x1 parity c
  #pragma unroll
  for (int c = 0; c < 2; ++c) {
    // conv1 MFMA for this chunk's 256 l1 voxels -> h1f (conv2 B-frag order)
    #pragma unroll
    for (int gi = 0; gi < 4; ++gi) {
      const int idx = (wid * 4 + gi) * 16 + l15;
      const int x1 = 2 * (idx >> 6) + c, y1 = (idx >> 3) & 7, z1 = idx & 7;
      const int base2 = (x1 * 100 + y1 * 10 + z1) * 2;
      f16x8 bf;
      #pragma unroll
      for (int j = 0; j < 8; ++j)
        bf[j] = *reinterpret_cast<const _Float16*>(tilec + base2 + t_off[j]);
      f32x4 aA = (f32x4){0.f, 0.f, 0.f, 0.f};
      f32x4 aB = (f32x4){0.f, 0.f, 0.f, 0.f};
      aA = __builtin_amdgcn_mfma_f32_16x16x32_f16(__builtin_bit_cast(f16x8, w1a), bf, aA, 0, 0, 0);
      aB = __builtin_amdgcn_mfma_f32_16x16x32_f16(__builtin_bit_cast(f16x8, w1b), bf, aB, 0, 0, 0);

      const int p_l = ((y1 & 1) << 1) | (z1 & 1);
      const int v2  = ((x1 >> 1) << 4) | ((y1 >> 1) << 2) | (z1 >> 1);
      const float mk = m1v[(x1 << 6) + (y1 << 3) + z1];
      f16x2 mk2; mk2.x = (_Float16)mk; mk2.y = (_Float16)mk;
      const _Float16 z0 = (_Float16)0;
      const int fbase = (((v2 >> 4) * 4 + p_l) * 64 + (v2 & 15)) * 8 + (l4 & 1) * 4;
      const int qsel = l4 >> 1;
      uint2 wA, wB;
      {
        f16x2 t0; t0.x = (_Float16)aA[0]; t0.y = (_Float16)aA[1];
        f16x2 t1; t1.x = (_Float16)aA[2]; t1.y = (_Float16)aA[3];
        t0.x = t0.x > z0 ? t0.x : z0; t0.y = t0.y > z0 ? t0.y : z0;
        t1.x = t1.x > z0 ? t1.x : z0; t1.y = t1.y > z0 ? t1.y : z0;
        t0 = t0 * mk2; t1 = t1 * mk2;
        wA.x = __builtin_bit_cast(unsigned, t0); wA.y = __builtin_bit_cast(unsigned, t1);
      }
      {
        f16x2 t0; t0.x = (_Float16)aB[0]; t0.y = (_Float16)aB[1];
        f16x2 t1; t1.x = (_Float16)aB[2]; t1.y = (_Float16)aB[3];
        t0.x = t0.x > z0 ? t0.x : z0; t0.y = t0.y > z0 ? t0.y : z0;
        t1.x = t1.x > z0 ? t1.x : z0; t1.y = t1.y > z0 ? t1.y : z0;
        t0 = t0 * mk2; t1 = t1 * mk2;
        wB.x = __builtin_bit_cast(unsigned, t0); wB.y = __builtin_bit_cast(unsigned, t1);
      }
      *reinterpret_cast<uint2*>(&h1f[fbase + qsel * 128])       = wA;   // ch 0-15
      *reinterpret_cast<uint2*>(&h1f[fbase + (2 + qsel) * 128]) = wB;   // ch 16-31
    }
    __syncthreads();                      // h1f chunk ready

    // conv2 partial: K-steps c*4 .. c*4+3
    #pragma unroll
    for (int ks = 0; ks < 4; ++ks) {
      const f16x8 af = __builtin_bit_cast(f16x8, w2r[c * 4 + ks]);
      #pragma unroll
      for (int nt = 0; nt < 4; ++nt) {
        const f16x8 bb = *reinterpret_cast<const f16x8*>(&h1f[((nt * 4 + ks) * 64 + lane) * 8]);
        acc[nt] = __builtin_amdgcn_mfma_f32_16x16x32_f16(af, bb, acc[nt], 0, 0, 0);
      }
    }
    __syncthreads();                      // reads done (chunk1 / h2s may overwrite)
  }

  if (tid < 8) {                           // m3 = max over 8 l2 children
    const int x3 = tid >> 2, y3 = (tid >> 1) & 1, z3 = tid & 1;
    float m = 0.f;
    #pragma unroll
    for (int p = 0; p < 8; ++p) {
      const int cv = (((2*x3 + (p>>2)) << 4) | ((2*y3 + ((p>>1)&1)) << 2) | (2*z3 + (p&1)));
      m = fmaxf(m, m2s[cv]);
    }
    m3s[tid] = m;
  }

  // prefetch W3 chunk 0 (4 K-steps)
  uint4 wa[4], wb2[4];
  #pragma unroll
  for (int j = 0; j < 4; ++j) {
    wa[j]  = W3fA[(wid * 16 + j) * 64 + lane];
    wb2[j] = W3fB[(wid * 16 + j) * 64 + lane];
  }

  // conv2 epilogue: relu*m2, pack f16 -> h2s overlay
  const int o0 = wid * 16 + l4 * 4;
  #pragma unroll
  for (int nt = 0; nt < 4; ++nt) {
    const int v2l = nt * 16 + l15;
    const float m2v = m2s[v2l];
    const float d0 = fmaxf(acc[nt][0], 0.f) * m2v;
    const float d1 = fmaxf(acc[nt][1], 0.f) * m2v;
    const float d2 = fmaxf(acc[nt][2], 0.f) * m2v;
    const float d3 = fmaxf(acc[nt][3], 0.f) * m2v;
    f16x2 p0; p0.x = (_Float16)d0; p0.y = (_Float16)d1;
    f16x2 p1; p1.x = (_Float16)d2; p1.y = (_Float16)d3;
    uint2 u; u.x = __builtin_bit_cast(unsigned, p0); u.y = __builtin_bit_cast(unsigned, p1);
    *reinterpret_cast<uint2*>(&h2s[v2l * 88 + o0]) = u;
  }
  __syncthreads();                                // h2s ready

  // ---- phase 3: conv3 MFMA, software-pipelined W3-frag stream, K=512
  f32x4 c3a = (f32x4){0.f,0.f,0.f,0.f};
  f32x4 c3b = (f32x4){0.f,0.f,0.f,0.f};
  const int v3 = l15 & 7;
  const int x3o = v3 >> 2, y3o = (v3 >> 1) & 1, z3o = v3 & 1;

  #pragma unroll
  for (int kc = 0; kc < 4; ++kc) {
    uint4 na[4], nb[4];
    if (kc < 3) {
      #pragma unroll
      for (int j = 0; j < 4; ++j) {
        na[j] = W3fA[(wid * 16 + (kc + 1) * 4 + j) * 64 + lane];
        nb[j] = W3fB[(wid * 16 + (kc + 1) * 4 + j) * 64 + lane];
      }
    }
    #pragma unroll
    for (int j = 0; j < 4; ++j) {
      const int ks = kc * 4 + j;
      const int p = ks >> 1;
      const int vox = (((2*x3o + (p>>2)) << 4) | ((2*y3o + ((p>>1)&1)) << 2) | (2*z3o + (p&1)));
      const int c0 = (ks & 1) * 32 + l4 * 8;
      const f16x8 bf = *reinterpret_cast<const f16x8*>(&h2s[vox * 88 + c0]);
      c3a = __builtin_amdgcn_mfma_f32_16x16x32_f16(__builtin_bit_cast(f16x8, wa[j]),  bf, c3a, 0, 0, 0);
      c3b = __builtin_amdgcn_mfma_f32_16x16x32_f16(__builtin_bit_cast(f16x8, wb2[j]), bf, c3b, 0, 0, 0);
    }
    if (kc < 3) {
      #pragma unroll
      for (int j = 0; j < 4; ++j) { wa[j] = na[j]; wb2[j] = nb[j]; }
    }
  }

  // relu * m3 (zero for duplicated N-half), reduce 16 lanes, bucket atomics
  const float m3v = (l15 < 8) ? m3s[v3] : 0.f;
  float part[2][4];
  #pragma unroll
  for (int j = 0; j < 4; ++j) {
    part[0][j] = fmaxf(c3a[j], 0.f) * m3v;
    part[1][j] = fmaxf(c3b[j], 0.f) * m3v;
  }
  #pragma unroll
  for (int d = 1; d < 16; d <<= 1) {
    #pragma unroll
    for (int mt = 0; mt < 2; ++mt)
      #pragma unroll
      for (int j = 0; j < 4; ++j)
        part[mt][j] += __shfl_xor(part[mt][j], d, 64);
  }
  if (l15 == 0) {
    const int sb = (b * 64 + (bid & 63)) * 128 + wid * 32;
    #pragma unroll
    for (int mt = 0; mt < 2; ++mt)
      #pragma unroll
      for (int j = 0; j < 4; ++j)
        atomicAdd(&spart[sb + mt * 16 + l4 * 4 + j], part[mt][j]);
  }
  if (tid == 0) {
    float t = 0.f;
    #pragma unroll
    for (int i = 0; i < 8; ++i) t += m3s[i];
    atomicAdd(&cntB[b * 64 + (bid & 63)], t);
  }
}

// ------------------------------------------------- bucket reduce + final FC
__global__ __launch_bounds__(256) void reduce_fc_k(
    const float* __restrict__ spart, const float* __restrict__ cntB,
    const float* __restrict__ fc_w, const float* __restrict__ fc_b,
    float* __restrict__ out)
{
  __shared__ float s_l[128];
  __shared__ float c_l;
  const int b = blockIdx.x, tid = threadIdx.x;
  if (tid < 128) {
    float a = 0.f;
    #pragma unroll 8
    for (int g = 0; g < 64; ++g) a += spart[(b * 64 + g) * 128 + tid];
    s_l[tid] = a;
  } else if (tid < 192) {
    float a = cntB[b * 64 + (tid - 128)];
    #pragma unroll
    for (int d = 1; d < 64; d <<= 1) a += __shfl_xor(a, d, 64);
    if (tid == 128) c_l = a;
  }
  __syncthreads();
  const float inv = 1.f / fmaxf(c_l, 1.f);
  float o = fc_b[tid];
  #pragma unroll 8
  for (int c = 0; c < 128; ++c) o = fmaf(s_l[c] * inv, fc_w[c * 256 + tid], o);
  out[b * 256 + tid] = o;
}

// ---------------------------------------------------------------- launch
extern "C" void kernel_launch(void* const* d_in, const int* in_sizes, int n_in,
                              void* d_out, int out_size, void* d_ws, size_t ws_size,
                              hipStream_t stream)
{
  const int*   coords = (const int*)  d_in[0];
  const float* feats  = (const float*)d_in[1];
  const float* W1     = (const float*)d_in[2];
  const float* W2     = (const float*)d_in[3];
  const float* W3     = (const float*)d_in[4];
  const float* fc_w   = (const float*)d_in[5];
  const float* fc_b   = (const float*)d_in[6];
  float* out = (float*)d_out;
  const int N = in_sizes[0] / 4;

  unsigned* gpk   = (unsigned*)d_ws;                 // 8.39 MB (f16 val, f16 cnt)
  float*    spart = (float*)(gpk + GRID_ELEMS);      // 256 KB (8 x 64 x 128)
  float*    cntB  = spart + 8 * 64 * 128;            // 2 KB
  uint4*    W1f   = (uint4*)(cntB + 512);            // 2 KB (128 uint4)
  uint4*    W2f   = W1f + 128;                       // 32 KB
  uint4*    W3fA  = W2f + 2048;                      // 64 KB
  uint4*    W3fB  = W3fA + 4096;                     // 64 KB
  // total ws use: ~8.8 MB

  // zero gpk + spart + cntB in one shot (contiguous)
  hipMemsetAsync(gpk, 0, (size_t)GRID_ELEMS * 4 + 65536 * 4 + 512 * 4, stream);

  scatter_setup_k<<<44 + (N + 255) / 256, 256, 0, stream>>>(
      coords, feats, W1, W2, W3, (__half2*)gpk, W1f, W2f, W3fA, W3fB, N);
  mega_k<<<4096, 256, 0, stream>>>(gpk, W1f, W2f, W3fA, W3fB, spart, cntB);
  reduce_fc_k<<<8, 256, 0, stream>>>(spart, cntB, fc_w, fc_b, out);
}

// Round 9
// 67.454 us; speedup vs baseline: 3.4141x; 1.1080x over previous
//
#include <hip/hip_runtime.h>
#include <hip/hip_bf16.h>
#include <hip/hip_fp16.h>

typedef __attribute__((ext_vector_type(2))) _Float16 f16x2;
typedef __attribute__((ext_vector_type(8))) _Float16 f16x8;
typedef __attribute__((ext_vector_type(4))) float    f32x4;

#define GRID_ELEMS (8*64*64*64)   // 2,097,152 voxels at level 0

// --------------------------------------------- scatter + weight-repack combo
// blocks [0,44): pre-fragment W1/W2/W3 into per-lane MFMA A-frag order.
// blocks [44,..): scatter points — ONE packed-f16 atomic adds (feat, 1.0)
// into gpk[voxel] = {lo: f16 value-sum, hi: f16 point-count}.
__global__ __launch_bounds__(256) void scatter_setup_k(
    const int* __restrict__ coords, const float* __restrict__ feats,
    const float* __restrict__ W1, const float* __restrict__ W2, const float* __restrict__ W3,
    __half2* __restrict__ gpk,
    uint4* __restrict__ W1f, uint4* __restrict__ W2f,
    uint4* __restrict__ W3fA, uint4* __restrict__ W3fB, int N)
{
  const int bi = blockIdx.x;
  if (bi < 44) {
    const int i = bi * 256 + threadIdx.x;
    if (i < 2048) {                       // W2f[(wid*8+ks)*64+lane]
      const int wid = i >> 9, ks = (i >> 6) & 7, lane = i & 63;
      const int l15 = lane & 15, l4 = lane >> 4, o = wid * 16 + l15;
      f16x8 v;
      #pragma unroll
      for (int j = 0; j < 8; ++j)          // k = ks*32 + l4*8 + j -> p=ks, c=l4*8+j
        v[j] = (_Float16)W2[ks * 2048 + (l4 * 8 + j) * 64 + o];
      W2f[i] = __builtin_bit_cast(uint4, v);
    } else if (i < 10240) {               // W3fA/B[(wid*16+ks)*64+lane]
      const int e = i - 2048, ab = e >> 12, r = e & 4095;
      const int wid = r >> 10, ks = (r >> 6) & 15, lane = r & 63;
      const int l15 = lane & 15, l4 = lane >> 4, o = wid * 32 + l15 + ab * 16;
      f16x8 v;
      #pragma unroll
      for (int j = 0; j < 8; ++j)          // k = ks*32+l4*8+j -> p=ks>>1, c=(ks&1)*32+l4*8+j
        v[j] = (_Float16)W3[(ks >> 1) * 8192 + ((ks & 1) * 32 + l4 * 8 + j) * 128 + o];
      (ab ? W3fB : W3fA)[r] = __builtin_bit_cast(uint4, v);
    } else if (i < 10368) {               // W1f[mt*64+lane]: A[m=ch][k=tap], k pad 27->32
      const int t = i - 10240;
      const int mt = t >> 6, l = t & 63;
      f16x8 v;
      #pragma unroll
      for (int j = 0; j < 8; ++j) {
        const int k = (l >> 4) * 8 + j;
        v[j] = (k < 27) ? (_Float16)W1[k * 32 + mt * 16 + (l & 15)] : (_Float16)0;
      }
      W1f[t] = __builtin_bit_cast(uint4, v);
    }
    return;
  }
  const int i = (bi - 44) * 256 + threadIdx.x;
  if (i >= N) return;
  const int4 c = reinterpret_cast<const int4*>(coords)[i];
  const int idx = ((c.x * 64 + c.y) * 64 + c.z) * 64 + c.w;
  const __half2 v = __halves2half2(__float2half_rn(feats[i]), __float2half_rn(1.0f));
  unsafeAtomicAdd(&gpk[idx], v);         // global_atomic_pk_add_f16
}

// --------------------------------------------------------------- megakernel
// Block = octant PAIR along z: 4x4x8 l2-voxels (8x8x16 l1, 2x2x4 l3).
// 2048 blocks. conv3 runs N=16 (both octants, no padded half) so W3's L2
// stream and conv3 MFMA are amortized 2x. h2s[oct1] overlays h1f after the
// last conv2 read. All three convs on MFMA; pooled sums -> 64-bucket atomics.
__global__ __launch_bounds__(256, 4) void mega_k(
    const unsigned* __restrict__ gpk,
    const uint4* __restrict__ W1f, const uint4* __restrict__ W2f,
    const uint4* __restrict__ W3fA, const uint4* __restrict__ W3fB,
    float* __restrict__ spart, float* __restrict__ cntB)
{
  // manual LDS carve (35,984 B): [h2s0 11264][h1f 16384 (h2s1 overlays)]
  // [tile 3600][m1v 4096][m2s 512][m3s 64][toff 64]
  __shared__ __align__(16) char smem[35984];
  _Float16* const h1f  = (_Float16*)(smem + 11264);
  _Float16* const tile = (_Float16*)(smem + 27648);        // [10][10][18]
  float*    const m1v  = (float*)(smem + 31248);           // [8][8][16]
  float*    const m2s  = (float*)(smem + 35344);           // [4][4][8]
  float*    const m3s  = (float*)(smem + 35856);           // [2][2][4]
  unsigned short* const toff = (unsigned short*)(smem + 35920);

  const int tid = threadIdx.x;
  const int bid = blockIdx.x;
  const int b   = bid >> 8;
  const int X2  = (bid >> 5) & 7, Y2 = (bid >> 2) & 7, Zp = bid & 3;
  const int gb  = b << 18;
  const int lane = tid & 63, wid = tid >> 6;
  const int l15 = lane & 15, l4 = lane >> 4;

  // ---- phase 0: stage grid tile (f16 val half) + l1 mask (cnt half)
  {
    const int gx0 = X2 * 8 - 1, gy0 = Y2 * 8 - 1, gz0 = Zp * 16 - 1;
    for (int e = tid; e < 1800; e += 256) {
      const int x = e / 180, r = e - x * 180, y = r / 18, z = r - y * 18;
      const int gx = gx0 + x, gy = gy0 + y, gz = gz0 + z;
      const bool ok = ((unsigned)gx < 64u) & ((unsigned)gy < 64u) & ((unsigned)gz < 64u);
      const unsigned g = ok ? gpk[gb + (gx << 12) + (gy << 6) + gz] : 0u;
      tile[e] = __builtin_bit_cast(_Float16, (unsigned short)(g & 0xffffu));
      const int ix = x - 1, iy = y - 1, iz = z - 1;
      if (((unsigned)ix < 8u) & ((unsigned)iy < 8u) & ((unsigned)iz < 16u))
        m1v[(ix << 7) + (iy << 4) + iz] = (g >> 16) ? 1.f : 0.f;
    }
  }
  if (tid < 32) {
    unsigned short off = 0;
    if (tid < 27) {
      const int tx = tid / 9, rr = tid - tx * 9, ty = rr / 3, tz = rr - ty * 3;
      off = (unsigned short)((tx * 180 + ty * 18 + tz) * 2);
    }
    toff[tid] = off;
  }

  // W-frag preloads (L2; latency hidden under phase 0)
  const uint4 w1a = W1f[lane];
  const uint4 w1b = W1f[64 + lane];
  uint4 w2r[8];
  #pragma unroll
  for (int ks = 0; ks < 8; ++ks) w2r[ks] = W2f[(wid * 8 + ks) * 64 + lane];

  __syncthreads();

  if (tid < 128) {   // m2 = max over 8 l1 children; [x2][y2][z2] 4x4x8
    const int base = ((tid >> 5) << 8) + (((tid >> 3) & 3) << 5) + ((tid & 7) << 1);
    float m = m1v[base];
    m = fmaxf(m, m1v[base + 1]);   m = fmaxf(m, m1v[base + 16]);
    m = fmaxf(m, m1v[base + 17]);  m = fmaxf(m, m1v[base + 128]);
    m = fmaxf(m, m1v[base + 129]); m = fmaxf(m, m1v[base + 144]);
    m = fmaxf(m, m1v[base + 145]);
    m2s[tid] = m;
  }

  int t_off[8];
  #pragma unroll
  for (int j = 0; j < 8; ++j) t_off[j] = toff[l4 * 8 + j];

  const char* tilec = (const char*)tile;
  uint4 wa[4], wb2[4];                    // W3 pipeline regs (filled at o==1)

  #pragma unroll
  for (int o = 0; o < 2; ++o) {
    f32x4 acc[4];
    #pragma unroll
    for (int nt = 0; nt < 4; ++nt) acc[nt] = (f32x4){0.f, 0.f, 0.f, 0.f};

    #pragma unroll
    for (int c = 0; c < 2; ++c) {
      // conv1 MFMA chunk: l1 voxels of octant o with x1 parity c
      #pragma unroll
      for (int gi = 0; gi < 4; ++gi) {
        const int idx = (wid * 4 + gi) * 16 + l15;
        const int x1 = 2 * (idx >> 6) + c, y1 = (idx >> 3) & 7, zo = idx & 7;
        const int z1 = o * 8 + zo;
        const int base2 = (x1 * 180 + y1 * 18 + z1) * 2;
        f16x8 bf;
        #pragma unroll
        for (int j = 0; j < 8; ++j)
          bf[j] = *reinterpret_cast<const _Float16*>(tilec + base2 + t_off[j]);
        f32x4 aA = (f32x4){0.f, 0.f, 0.f, 0.f};
        f32x4 aB = (f32x4){0.f, 0.f, 0.f, 0.f};
        aA = __builtin_amdgcn_mfma_f32_16x16x32_f16(__builtin_bit_cast(f16x8, w1a), bf, aA, 0, 0, 0);
        aB = __builtin_amdgcn_mfma_f32_16x16x32_f16(__builtin_bit_cast(f16x8, w1b), bf, aB, 0, 0, 0);

        const int p_l = ((y1 & 1) << 1) | (zo & 1);
        const int v2  = ((x1 >> 1) << 4) | ((y1 >> 1) << 2) | (zo >> 1);
        const float mk = m1v[(x1 << 7) + (y1 << 4) + z1];
        f16x2 mk2; mk2.x = (_Float16)mk; mk2.y = (_Float16)mk;
        const _Float16 z0 = (_Float16)0;
        const int fbase = (((v2 >> 4) * 4 + p_l) * 64 + (v2 & 15)) * 8 + (l4 & 1) * 4;
        const int qsel = l4 >> 1;
        uint2 wA, wB;
        {
          f16x2 t0; t0.x = (_Float16)aA[0]; t0.y = (_Float16)aA[1];
          f16x2 t1; t1.x = (_Float16)aA[2]; t1.y = (_Float16)aA[3];
          t0.x = t0.x > z0 ? t0.x : z0; t0.y = t0.y > z0 ? t0.y : z0;
          t1.x = t1.x > z0 ? t1.x : z0; t1.y = t1.y > z0 ? t1.y : z0;
          t0 = t0 * mk2; t1 = t1 * mk2;
          wA.x = __builtin_bit_cast(unsigned, t0); wA.y = __builtin_bit_cast(unsigned, t1);
        }
        {
          f16x2 t0; t0.x = (_Float16)aB[0]; t0.y = (_Float16)aB[1];
          f16x2 t1; t1.x = (_Float16)aB[2]; t1.y = (_Float16)aB[3];
          t0.x = t0.x > z0 ? t0.x : z0; t0.y = t0.y > z0 ? t0.y : z0;
          t1.x = t1.x > z0 ? t1.x : z0; t1.y = t1.y > z0 ? t1.y : z0;
          t0 = t0 * mk2; t1 = t1 * mk2;
          wB.x = __builtin_bit_cast(unsigned, t0); wB.y = __builtin_bit_cast(unsigned, t1);
        }
        *reinterpret_cast<uint2*>(&h1f[fbase + qsel * 128])       = wA;   // ch 0-15
        *reinterpret_cast<uint2*>(&h1f[fbase + (2 + qsel) * 128]) = wB;   // ch 16-31
      }
      __syncthreads();                    // h1f chunk ready

      if (o == 0 && c == 0 && tid < 16) { // m3 = max over 8 l2 children; [2][2][4]
        const int base = ((tid >> 3) << 6) + (((tid >> 2) & 1) << 4) + ((tid & 3) << 1);
        float m = m2s[base];
        m = fmaxf(m, m2s[base + 1]);  m = fmaxf(m, m2s[base + 8]);
        m = fmaxf(m, m2s[base + 9]);  m = fmaxf(m, m2s[base + 32]);
        m = fmaxf(m, m2s[base + 33]); m = fmaxf(m, m2s[base + 40]);
        m = fmaxf(m, m2s[base + 41]);
        m3s[tid] = m;
      }

      // conv2 partial: K-steps c*4 .. c*4+3
      #pragma unroll
      for (int ks = 0; ks < 4; ++ks) {
        const f16x8 af = __builtin_bit_cast(f16x8, w2r[c * 4 + ks]);
        #pragma unroll
        for (int nt = 0; nt < 4; ++nt) {
          const f16x8 bb = *reinterpret_cast<const f16x8*>(&h1f[((nt * 4 + ks) * 64 + lane) * 8]);
          acc[nt] = __builtin_amdgcn_mfma_f32_16x16x32_f16(af, bb, acc[nt], 0, 0, 0);
        }
      }

      if (o == 1 && c == 1) {             // prefetch W3 chunk 0 under barrier+epilogue
        #pragma unroll
        for (int j = 0; j < 4; ++j) {
          wa[j]  = W3fA[(wid * 16 + j) * 64 + lane];
          wb2[j] = W3fB[(wid * 16 + j) * 64 + lane];
        }
      }
      __syncthreads();                    // conv2 reads done (h1f reusable)
    }

    // conv2 epilogue: relu*m2, pack f16 -> h2s[o] (o=1 overlays h1f start)
    _Float16* const h2o = (_Float16*)(smem + o * 11264);
    const int o0 = wid * 16 + l4 * 4;
    #pragma unroll
    for (int nt = 0; nt < 4; ++nt) {
      const int v2l = nt * 16 + l15;
      const float m2v = m2s[((v2l >> 4) << 5) + (((v2l >> 2) & 3) << 3) + o * 4 + (v2l & 3)];
      const float d0 = fmaxf(acc[nt][0], 0.f) * m2v;
      const float d1 = fmaxf(acc[nt][1], 0.f) * m2v;
      const float d2 = fmaxf(acc[nt][2], 0.f) * m2v;
      const float d3 = fmaxf(acc[nt][3], 0.f) * m2v;
      f16x2 p0; p0.x = (_Float16)d0; p0.y = (_Float16)d1;
      f16x2 p1; p1.x = (_Float16)d2; p1.y = (_Float16)d3;
      uint2 u; u.x = __builtin_bit_cast(unsigned, p0); u.y = __builtin_bit_cast(unsigned, p1);
      *reinterpret_cast<uint2*>(&h2o[v2l * 88 + o0]) = u;
    }
  }
  __syncthreads();                        // h2s0 + h2s1 ready

  // ---- conv3 MFMA: N=16 l3-voxels (both octants), K=512, pipelined W3 stream
  f32x4 c3a = (f32x4){0.f,0.f,0.f,0.f};
  f32x4 c3b = (f32x4){0.f,0.f,0.f,0.f};
  const int v3 = l15;                     // [x3 2][y3 2][z3 4]
  const int x3 = v3 >> 3, y3 = (v3 >> 2) & 1, z3 = v3 & 3;
  const int obyte = (z3 >> 1) * 11264;

  #pragma unroll
  for (int kc = 0; kc < 4; ++kc) {
    uint4 na[4], nb[4];
    if (kc < 3) {
      #pragma unroll
      for (int j = 0; j < 4; ++j) {
        na[j] = W3fA[(wid * 16 + (kc + 1) * 4 + j) * 64 + lane];
        nb[j] = W3fB[(wid * 16 + (kc + 1) * 4 + j) * 64 + lane];
      }
    }
    #pragma unroll
    for (int j = 0; j < 4; ++j) {
      const int ks = kc * 4 + j;
      const int p = ks >> 1;
      const int x2 = 2 * x3 + (p >> 2), y2 = 2 * y3 + ((p >> 1) & 1);
      const int z2l = 2 * (z3 & 1) + (p & 1);
      const int v2l = (x2 << 4) | (y2 << 2) | z2l;
      const int c0 = (ks & 1) * 32 + l4 * 8;
      const f16x8 bf = *reinterpret_cast<const f16x8*>(smem + obyte + (v2l * 88 + c0) * 2);
      c3a = __builtin_amdgcn_mfma_f32_16x16x32_f16(__builtin_bit_cast(f16x8, wa[j]),  bf, c3a, 0, 0, 0);
      c3b = __builtin_amdgcn_mfma_f32_16x16x32_f16(__builtin_bit_cast(f16x8, wb2[j]), bf, c3b, 0, 0, 0);
    }
    if (kc < 3) {
      #pragma unroll
      for (int j = 0; j < 4; ++j) { wa[j] = na[j]; wb2[j] = nb[j]; }
    }
  }

  // relu * m3, reduce over the 16 voxel-lanes, bucket atomics
  const float m3v = m3s[v3];
  float part[2][4];
  #pragma unroll
  for (int j = 0; j < 4; ++j) {
    part[0][j] = fmaxf(c3a[j], 0.f) * m3v;
    part[1][j] = fmaxf(c3b[j], 0.f) * m3v;
  }
  #pragma unroll
  for (int d = 1; d < 16; d <<= 1) {
    #pragma unroll
    for (int mt = 0; mt < 2; ++mt)
      #pragma unroll
      for (int j = 0; j < 4; ++j)
        part[mt][j] += __shfl_xor(part[mt][j], d, 64);
  }
  if (l15 == 0) {
    const int sb = (b * 64 + (bid & 63)) * 128 + wid * 32;
    #pragma unroll
    for (int mt = 0; mt < 2; ++mt)
      #pragma unroll
      for (int j = 0; j < 4; ++j)
        atomicAdd(&spart[sb + mt * 16 + l4 * 4 + j], part[mt][j]);
  }
  if (tid == 0) {
    float t = 0.f;
    #pragma unroll
    for (int i = 0; i < 16; ++i) t += m3s[i];
    atomicAdd(&cntB[b * 64 + (bid & 63)], t);
  }
}

// ------------------------------------------------- bucket reduce + final FC
__global__ __launch_bounds__(256) void reduce_fc_k(
    const float* __restrict__ spart, const float* __restrict__ cntB,
    const float* __restrict__ fc_w, const float* __restrict__ fc_b,
    float* __restrict__ out)
{
  __shared__ float s_l[128];
  __shared__ float c_l;
  const int b = blockIdx.x, tid = threadIdx.x;
  if (tid < 128) {
    float a = 0.f;
    #pragma unroll 8
    for (int g = 0; g < 64; ++g) a += spart[(b * 64 + g) * 128 + tid];
    s_l[tid] = a;
  } else if (tid < 192) {
    float a = cntB[b * 64 + (tid - 128)];
    #pragma unroll
    for (int d = 1; d < 64; d <<= 1) a += __shfl_xor(a, d, 64);
    if (tid == 128) c_l = a;
  }
  __syncthreads();
  const float inv = 1.f / fmaxf(c_l, 1.f);
  float o = fc_b[tid];
  #pragma unroll 8
  for (int c = 0; c < 128; ++c) o = fmaf(s_l[c] * inv, fc_w[c * 256 + tid], o);
  out[b * 256 + tid] = o;
}

// ---------------------------------------------------------------- launch
extern "C" void kernel_launch(void* const* d_in, const int* in_sizes, int n_in,
                              void* d_out, int out_size, void* d_ws, size_t ws_size,
                              hipStream_t stream)
{
  const int*   coords = (const int*)  d_in[0];
  const float* feats  = (const float*)d_in[1];
  const float* W1     = (const float*)d_in[2];
  const float* W2     = (const float*)d_in[3];
  const float* W3     = (const float*)d_in[4];
  const float* fc_w   = (const float*)d_in[5];
  const float* fc_b   = (const float*)d_in[6];
  float* out = (float*)d_out;
  const int N = in_sizes[0] / 4;

  unsigned* gpk   = (unsigned*)d_ws;                 // 8.39 MB (f16 val, f16 cnt)
  float*    spart = (float*)(gpk + GRID_ELEMS);      // 256 KB (8 x 64 x 128)
  float*    cntB  = spart + 8 * 64 * 128;            // 2 KB
  uint4*    W1f   = (uint4*)(cntB + 512);            // 2 KB (128 uint4)
  uint4*    W2f   = W1f + 128;                       // 32 KB
  uint4*    W3fA  = W2f + 2048;                      // 64 KB
  uint4*    W3fB  = W3fA + 4096;                     // 64 KB
  // total ws use: ~8.8 MB

  // zero gpk + spart + cntB in one shot (contiguous)
  hipMemsetAsync(gpk, 0, (size_t)GRID_ELEMS * 4 + 65536 * 4 + 512 * 4, stream);

  scatter_setup_k<<<44 + (N + 255) / 256, 256, 0, stream>>>(
      coords, feats, W1, W2, W3, (__half2*)gpk, W1f, W2f, W3fA, W3fB, N);
  mega_k<<<2048, 256, 0, stream>>>(gpk, W1f, W2f, W3fA, W3fB, spart, cntB);
  reduce_fc_k<<<8, 256, 0, stream>>>(spart, cntB, fc_w, fc_b, out);
}